// Round 4
// baseline (1121.311 us; speedup 1.0000x reference)
//
#include <hip/hip_runtime.h>
#include <stdint.h>

typedef __attribute__((ext_vector_type(8))) short bf16x8;
typedef __attribute__((ext_vector_type(4))) float f32x4;

#define NCH 8           // edge chunks (chunk size CH is 1024-aligned, host-computed)
#define NRNG 8          // node-id ranges
#define HWORDS 6272     // packed u32 words (2 u16 bins each) >= ceil(12500/2); 25088B LDS

static __device__ __forceinline__ unsigned short f2bf(float f){
  unsigned int u = __float_as_uint(f);
  return (unsigned short)((u + 0x7fffu + ((u >> 16) & 1u)) >> 16);
}
static __device__ __forceinline__ float bf2f(unsigned short h){
  return __uint_as_float(((unsigned int)h) << 16);
}

static __device__ __forceinline__ void gld_lds16(const void* g, void* l){
  __builtin_amdgcn_global_load_lds((__attribute__((address_space(1))) void*)(void*)g,
                                   (__attribute__((address_space(3))) void*)l, 16, 0, 0);
}

// ---------------- fused: LDS-binned edge histograms (+rank record) + fp32->bf16 ----------------
// Rounds 0-2: gfx950 global atomics are always memory-side (~32B write-through,
// ~25G/s) -> all graph-build atomics must be LDS. Round 3: the standalone
// LDS-scatter was parallelism-starved (128 blocks, 5.6% occupancy, 172us).
// Fix: the cnt-histogram's LDS atomicAdd ALREADY yields each edge's rank
// within (chunk,key) — persist it (eRank u16), and scatter becomes an
// E-parallel atomic-free map. Bins packed 2xu16/u32 -> 25KB LDS (6 blk/CU),
// un-throttling the fused conversion blocks.
// blocks: [0,HB): deg-hist; [HB,2HB): cnt-hist+rank; then x/w1 converts, w2pad.
__global__ __launch_bounds__(256) void k_mega(
    const int* __restrict__ ei, int E, int CH,
    int* __restrict__ Gdeg, int* __restrict__ Gcnt,
    unsigned short* __restrict__ eRank, int Nn,
    const float* __restrict__ x, unsigned short* __restrict__ xb, int nx,
    const float* __restrict__ w1, unsigned short* __restrict__ w1b, int nw1,
    const float* __restrict__ w2, unsigned short* __restrict__ w2p,
    int XB, int W1B)
{
  __shared__ unsigned hist[HWORDS];
  const int HB = NCH * NRNG;
  int b = blockIdx.x;
  if (b < 2 * HB){
    int isCnt = (b >= HB);
    int hb = isCnt ? b - HB : b;
    int c = hb >> 3, r = hb & 7;                 // NRNG = 8
    int BIN = (Nn + NRNG - 1) / NRNG;
    int r0 = r * BIN;
    int bc = Nn - r0; if (bc > BIN) bc = BIN;
    int words = (bc + 1) >> 1;
    const int* keys = ei + (isCnt ? E : 0);
    int* G = (isCnt ? Gcnt : Gdeg) + (size_t)c * Nn + r0;
    for (int i = threadIdx.x; i < words; i += 256) hist[i] = 0;
    __syncthreads();
    int cs = c * CH;
    int ce = E - cs; if (ce > CH) ce = CH;       // edges in this chunk
    const int* kc = keys + cs;
    int nv = ce >> 2;
    if (isCnt){
      unsigned short* rk = eRank + cs;
      for (int v = threadIdx.x; v < nv; v += 256){
        int4 k4 = *(const int4*)(kc + v * 4);
        int t, sh; unsigned ret;
#define CNT1(KK, UU) \
        t = KK - r0; \
        if ((unsigned)t < (unsigned)bc){ \
          sh = (t & 1) << 4; \
          ret = atomicAdd(&hist[t >> 1], 1u << sh); \
          rk[v * 4 + UU] = (unsigned short)((ret >> sh) & 0xffffu); \
        }
        CNT1(k4.x, 0) CNT1(k4.y, 1) CNT1(k4.z, 2) CNT1(k4.w, 3)
#undef CNT1
      }
      for (int j = nv * 4 + threadIdx.x; j < ce; j += 256){
        int t = kc[j] - r0;
        if ((unsigned)t < (unsigned)bc){
          int sh = (t & 1) << 4;
          unsigned ret = atomicAdd(&hist[t >> 1], 1u << sh);
          rk[j] = (unsigned short)((ret >> sh) & 0xffffu);
        }
      }
    } else {
      for (int v = threadIdx.x; v < nv; v += 256){
        int4 k4 = *(const int4*)(kc + v * 4);
        int t;
        t = k4.x - r0; if ((unsigned)t < (unsigned)bc) atomicAdd(&hist[t >> 1], 1u << ((t & 1) << 4));
        t = k4.y - r0; if ((unsigned)t < (unsigned)bc) atomicAdd(&hist[t >> 1], 1u << ((t & 1) << 4));
        t = k4.z - r0; if ((unsigned)t < (unsigned)bc) atomicAdd(&hist[t >> 1], 1u << ((t & 1) << 4));
        t = k4.w - r0; if ((unsigned)t < (unsigned)bc) atomicAdd(&hist[t >> 1], 1u << ((t & 1) << 4));
      }
      for (int j = nv * 4 + threadIdx.x; j < ce; j += 256){
        int t = kc[j] - r0;
        if ((unsigned)t < (unsigned)bc) atomicAdd(&hist[t >> 1], 1u << ((t & 1) << 4));
      }
    }
    __syncthreads();
    for (int i = threadIdx.x; i < bc; i += 256)
      G[i] = (int)((hist[i >> 1] >> ((i & 1) << 4)) & 0xffffu);
  } else if (b < 2 * HB + XB){
    int i = ((b - 2 * HB) * 256 + threadIdx.x) * 8;
    if (i + 8 <= nx){
      float4 a = *(const float4*)(x + i);
      float4 c = *(const float4*)(x + i + 4);
      ushort4 r0 = { f2bf(a.x), f2bf(a.y), f2bf(a.z), f2bf(a.w) };
      ushort4 r1 = { f2bf(c.x), f2bf(c.y), f2bf(c.z), f2bf(c.w) };
      *(ushort4*)(xb + i) = r0;
      *(ushort4*)(xb + i + 4) = r1;
    } else {
      for (int j = i; j < nx; ++j) xb[j] = f2bf(x[j]);
    }
  } else if (b < 2 * HB + XB + W1B){
    int i = ((b - 2 * HB - XB) * 256 + threadIdx.x) * 8;
    if (i + 8 <= nw1){
      float4 a = *(const float4*)(w1 + i);
      float4 c = *(const float4*)(w1 + i + 4);
      ushort4 r0 = { f2bf(a.x), f2bf(a.y), f2bf(a.z), f2bf(a.w) };
      ushort4 r1 = { f2bf(c.x), f2bf(c.y), f2bf(c.z), f2bf(c.w) };
      *(ushort4*)(w1b + i) = r0;
      *(ushort4*)(w1b + i + 4) = r1;
    } else {
      for (int j = i; j < nw1; ++j) w1b[j] = f2bf(w1[j]);
    }
  } else {
    int e = (b - 2 * HB - XB - W1B) * 256 + threadIdx.x;   // 48*256 elems
    int r = e >> 8, c = e & 255;
    float v = (r < 40) ? w2[r * 256 + c] : 0.f;
    w2p[e] = f2bf(v);
  }
}

// ---------------- GEMM1: H = relu(X @ W1^T + b1), bf16 in, bf16 out ----------------
__global__ __launch_bounds__(256) void k_gemm1(
    const unsigned short* __restrict__ A,   // M x 512 bf16
    const unsigned short* __restrict__ B,   // 256 x 512 bf16
    const float* __restrict__ bias,         // 256 fp32
    unsigned short* __restrict__ H,         // M x 256 bf16
    int M)
{
  __shared__ __align__(16) unsigned short lA[128 * 32];
  __shared__ __align__(16) unsigned short lB[128 * 32];
  const int K = 512;
  int tid = threadIdx.x;
  int wave = tid >> 6, lane = tid & 63;
  int quad = lane >> 4, l16 = lane & 15;
  int rowBase = blockIdx.x * 128;
  int colBase = blockIdx.y * 128;
  int wm = (wave & 1) * 64, wn = (wave >> 1) * 64;

  f32x4 acc[4][4] = {};

  for (int k0 = 0; k0 < K; k0 += 32){
#pragma unroll
    for (int i = 0; i < 2; ++i){
      int issue = wave * 2 + i;
      int s = issue * 64 + lane;
      int r = s >> 2;
      int c = (s & 3) ^ (r & 3);
      int gr = rowBase + r; if (gr >= M) gr = M - 1;
      gld_lds16(A + (size_t)gr * K + k0 + c * 8, (char*)lA + issue * 1024);
      gld_lds16(B + (size_t)(colBase + r) * K + k0 + c * 8, (char*)lB + issue * 1024);
    }
    __syncthreads();
    bf16x8 af[4], bf[4];
#pragma unroll
    for (int mt = 0; mt < 4; ++mt){
      int r = wm + mt * 16 + l16;
      af[mt] = *(const bf16x8*)&lA[r * 32 + ((quad ^ (r & 3)) * 8)];
    }
#pragma unroll
    for (int nt = 0; nt < 4; ++nt){
      int r = wn + nt * 16 + l16;
      bf[nt] = *(const bf16x8*)&lB[r * 32 + ((quad ^ (r & 3)) * 8)];
    }
#pragma unroll
    for (int mt = 0; mt < 4; ++mt)
#pragma unroll
      for (int nt = 0; nt < 4; ++nt)
        acc[mt][nt] = __builtin_amdgcn_mfma_f32_16x16x32_bf16(af[mt], bf[nt], acc[mt][nt], 0, 0, 0);
    __syncthreads();
  }

#pragma unroll
  for (int nt = 0; nt < 4; ++nt){
    int col = colBase + wn + nt * 16 + l16;
    float bb = bias[col];
#pragma unroll
    for (int mt = 0; mt < 4; ++mt){
#pragma unroll
      for (int rr = 0; rr < 4; ++rr){
        int row = rowBase + wm + mt * 16 + quad * 4 + rr;
        if (row < M){
          float v = acc[mt][nt][rr] + bb;
          v = v > 0.f ? v : 0.f;
          H[(size_t)row * 256 + col] = f2bf(v);
        }
      }
    }
  }
}

// ---------------- GEMM2: FT = H @ W2^T + b2 (fp32 out) ----------------
__global__ __launch_bounds__(256) void k_gemm2(
    const unsigned short* __restrict__ H,
    const unsigned short* __restrict__ W2p,
    const float* __restrict__ b2,
    float* __restrict__ ft,
    int M)
{
  __shared__ __align__(16) unsigned short lW[48 * 264];
  int tid = threadIdx.x;
  int wave = tid >> 6, lane = tid & 63;
  int quad = lane >> 4, l16 = lane & 15;

  for (int idx = tid; idx < 48 * 32; idx += 256){
    int r = idx >> 5, c = idx & 31;
    *(bf16x8*)&lW[r * 264 + c * 8] = *(const bf16x8*)&W2p[r * 256 + c * 8];
  }
  __syncthreads();

  int row0 = blockIdx.x * 64 + wave * 16;
  f32x4 acc[3] = {};
  int r = row0 + l16; if (r >= M) r = M - 1;
#pragma unroll
  for (int ks = 0; ks < 8; ++ks){
    bf16x8 af = *(const bf16x8*)&H[(size_t)r * 256 + ks * 32 + quad * 8];
#pragma unroll
    for (int nt = 0; nt < 3; ++nt){
      bf16x8 bf = *(const bf16x8*)&lW[(nt * 16 + l16) * 264 + ks * 32 + quad * 8];
      acc[nt] = __builtin_amdgcn_mfma_f32_16x16x32_bf16(af, bf, acc[nt], 0, 0, 0);
    }
  }
#pragma unroll
  for (int nt = 0; nt < 3; ++nt){
    int col = nt * 16 + l16;
    if (col < 40){
      float bb = b2[col];
#pragma unroll
      for (int rr = 0; rr < 4; ++rr){
        int row = row0 + quad * 4 + rr;
        if (row < M) ft[(size_t)row * 40 + col] = acc[nt][rr] + bb;
      }
    }
  }
}

// ---------------- graph prep ----------------
__global__ void k_dis(const int* __restrict__ Gdeg, const int* __restrict__ mask,
                      float* __restrict__ dis, float* __restrict__ dis2,
                      int* __restrict__ list, int* __restrict__ nUn, int n){
  int i = blockIdx.x * 256 + threadIdx.x;
  if (i < n){
    int dsum = 0;
#pragma unroll
    for (int c = 0; c < NCH; ++c) dsum += Gdeg[(size_t)c * n + i];
    float d = rsqrtf((float)(dsum + 1));
    dis[i] = d; dis2[i] = d * d;
    if (!mask[i]){ int pos = atomicAdd(nUn, 1); list[pos] = i; }
  }
}

// exclusive scan over in-counts (sum of Gcnt chunks + 1 self, ALL nodes;
// masked nodes' CSC lists are built but never read)
__global__ void k_scan1(const int* __restrict__ Gcnt,
                        int* __restrict__ out, int* __restrict__ bsum, int n){
  __shared__ int ts[256];
  int tid = threadIdx.x;
  int base = blockIdx.x * 1024 + tid * 4;
  int v0 = 0, v1 = 0, v2 = 0, v3 = 0;
  if (base + 4 <= n){
#pragma unroll
    for (int c = 0; c < NCH; ++c){
      int4 cc = *(const int4*)(Gcnt + (size_t)c * n + base);
      v0 += cc.x; v1 += cc.y; v2 += cc.z; v3 += cc.w;
    }
    v0 += 1; v1 += 1; v2 += 1; v3 += 1;
  } else if (base < n){
    int vv[4] = {0, 0, 0, 0};
    for (int j = 0; j < 4 && base + j < n; ++j){
      int s = 0;
      for (int c = 0; c < NCH; ++c) s += Gcnt[(size_t)c * n + base + j];
      vv[j] = s + 1;
    }
    v0 = vv[0]; v1 = vv[1]; v2 = vv[2]; v3 = vv[3];
  }
  int tot = v0 + v1 + v2 + v3;
  ts[tid] = tot; __syncthreads();
  int val = tot;
  for (int d = 1; d < 256; d <<= 1){
    int t = (tid >= d) ? ts[tid - d] : 0;
    __syncthreads();
    val += t; ts[tid] = val;
    __syncthreads();
  }
  int ex = val - tot;
  if (base     < n) out[base]     = ex;
  if (base + 1 < n) out[base + 1] = ex + v0;
  if (base + 2 < n) out[base + 2] = ex + v0 + v1;
  if (base + 3 < n) out[base + 3] = ex + v0 + v1 + v2;
  if (tid == 255) bsum[blockIdx.x] = val;
}
__global__ void k_scan2(int* __restrict__ bsum, int nb, int* __restrict__ offN){
  __shared__ int ts[256];
  int tid = threadIdx.x;
  int v = (tid < nb) ? bsum[tid] : 0;
  ts[tid] = v; __syncthreads();
  int val = v;
  for (int d = 1; d < 256; d <<= 1){
    int t = (tid >= d) ? ts[tid - d] : 0;
    __syncthreads();
    val += t; ts[tid] = val;
    __syncthreads();
  }
  if (tid < nb) bsum[tid] = val - v;
  if (tid == 255) *offN = val;
}
// finalize offsets; write self-loop entry for ALL nodes
__global__ void k_scan3(int* __restrict__ off, const int* __restrict__ bsum,
                        int* __restrict__ srcA, int n){
  int base = blockIdx.x * 1024 + threadIdx.x * 4;
  int add = bsum[blockIdx.x];
#pragma unroll
  for (int i = 0; i < 4; ++i){
    int j = base + i;
    if (j < n){
      int v = off[j] + add; off[j] = v;
      srcA[v] = j;
    }
  }
}

// turn Gcnt[c][key] counts into per-(chunk,key) scatter bases:
// base[c][key] = offs[key] + 1(self) + sum_{c'<c} Gcnt[c'][key]
__global__ void k_prefixG(int* __restrict__ Gcnt, const int* __restrict__ offs, int n){
  int i = blockIdx.x * 256 + threadIdx.x;
  if (i >= n) return;
  int s = offs[i] + 1;
#pragma unroll
  for (int c = 0; c < NCH; ++c){
    int t = Gcnt[(size_t)c * n + i];
    Gcnt[(size_t)c * n + i] = s;
    s += t;
  }
}

// E-parallel atomic-free scatter: slot = Gbase[chunk][col] + eRank[e].
// cdiv = CH/1024; CH is 1024-aligned so a 1024-edge block stays in one chunk.
__global__ __launch_bounds__(256) void k_scatter_flat(
    const int* __restrict__ ei, int E, int cdiv,
    const int* __restrict__ Gbase, int n,
    const unsigned short* __restrict__ eRank, int* __restrict__ srcA)
{
  int bid = blockIdx.x;
  int c = bid / cdiv;
  const int* gb = Gbase + (size_t)c * n;
  int e0 = bid * 1024 + threadIdx.x * 4;
  if (e0 + 4 <= E){
    int4 c4 = *(const int4*)(ei + E + e0);
    int4 r4 = *(const int4*)(ei + e0);
    ushort4 k4 = *(const ushort4*)(eRank + e0);
    srcA[gb[c4.x] + k4.x] = r4.x;
    srcA[gb[c4.y] + k4.y] = r4.y;
    srcA[gb[c4.z] + k4.z] = r4.z;
    srcA[gb[c4.w] + k4.w] = r4.w;
  } else {
    for (int e = e0; e < E; ++e)
      srcA[gb[ei[E + e]] + eRank[e]] = ei[e];
  }
}

// scaled-label init (packed u32 = 2 bf16 channels per word, 20 words/node)
__global__ void k_init_ps(const float* __restrict__ linit, const float* __restrict__ hard,
                          const float* __restrict__ dis, const int* __restrict__ mask,
                          unsigned* __restrict__ psI, unsigned* __restrict__ psA,
                          unsigned* __restrict__ psB, int nWords){
  int w = blockIdx.x * 256 + threadIdx.x;
  if (w >= nWords) return;
  int node = w / 20, l = w % 20;
  float d = dis[node];
  float2 li = *(const float2*)(linit + (size_t)node * 40 + 2 * l);
  unsigned lo = f2bf(li.x * d), hi = f2bf(li.y * d);
  psI[w] = lo | (hi << 16);
  if (mask[node]){
    float2 hv = *(const float2*)(hard + (size_t)node * 40 + 2 * l);
    unsigned pk = (unsigned)f2bf(hv.x * d) | ((unsigned)f2bf(hv.y * d) << 16);
    psA[w] = pk; psB[w] = pk;
  }
}

// ---------------- label propagation (8-way unroll) ----------------
// ps_out[c] = dis2[c] * sum_{r in CSC(c)} ps_in[r]   (scaled labels, bf16)
__global__ __launch_bounds__(256) void k_prop(
    const int* __restrict__ offs, const int* __restrict__ srcA,
    const int* __restrict__ list, const int* __restrict__ nUn,
    const float* __restrict__ dis2,
    const unsigned short* __restrict__ pin, unsigned short* __restrict__ pout)
{
  int widx = blockIdx.x * 4 + (threadIdx.x >> 6);
  if (widx >= *nUn) return;
  int node = __builtin_amdgcn_readfirstlane(list[widx]);
  int lane = threadIdx.x & 63;
  if (lane >= 40) return;
  int s = offs[node], e = offs[node + 1];
  float a0 = 0.f, a1 = 0.f, a2 = 0.f, a3 = 0.f;
  int i = s;
  for (; i + 8 <= e; i += 8){
    int s0 = srcA[i],     s1 = srcA[i + 1], s2 = srcA[i + 2], s3 = srcA[i + 3];
    int s4 = srcA[i + 4], s5 = srcA[i + 5], s6 = srcA[i + 6], s7 = srcA[i + 7];
    a0 += bf2f(pin[s0 * 40 + lane]);
    a1 += bf2f(pin[s1 * 40 + lane]);
    a2 += bf2f(pin[s2 * 40 + lane]);
    a3 += bf2f(pin[s3 * 40 + lane]);
    a0 += bf2f(pin[s4 * 40 + lane]);
    a1 += bf2f(pin[s5 * 40 + lane]);
    a2 += bf2f(pin[s6 * 40 + lane]);
    a3 += bf2f(pin[s7 * 40 + lane]);
  }
  for (; i + 4 <= e; i += 4){
    int s0 = srcA[i], s1 = srcA[i + 1], s2 = srcA[i + 2], s3 = srcA[i + 3];
    a0 += bf2f(pin[s0 * 40 + lane]);
    a1 += bf2f(pin[s1 * 40 + lane]);
    a2 += bf2f(pin[s2 * 40 + lane]);
    a3 += bf2f(pin[s3 * 40 + lane]);
  }
  for (; i < e; ++i) a0 += bf2f(pin[srcA[i] * 40 + lane]);
  pout[node * 40 + lane] = f2bf(dis2[node] * ((a0 + a1) + (a2 + a3)));
}

// final step fused with sigmoid-gate combine; covers ALL nodes
__global__ __launch_bounds__(256) void k_prop_final(
    const int* __restrict__ offs, const int* __restrict__ srcA,
    const float* __restrict__ dis, const unsigned short* __restrict__ pin,
    const int* __restrict__ mask, const float* __restrict__ hard,
    const float* __restrict__ alpha, const float* __restrict__ ft,
    float* __restrict__ outp, int n)
{
  int node = blockIdx.x * 4 + (threadIdx.x >> 6);
  if (node >= n) return;
  node = __builtin_amdgcn_readfirstlane(node);
  int lane = threadIdx.x & 63;
  if (lane >= 40) return;
  float a = 1.f / (1.f + __expf(-alpha[node]));
  float v;
  if (mask[node]){
    v = hard[(size_t)node * 40 + lane];
  } else {
    int s = offs[node], e = offs[node + 1];
    float a0 = 0.f, a1 = 0.f, a2 = 0.f, a3 = 0.f;
    int i = s;
    for (; i + 8 <= e; i += 8){
      int s0 = srcA[i],     s1 = srcA[i + 1], s2 = srcA[i + 2], s3 = srcA[i + 3];
      int s4 = srcA[i + 4], s5 = srcA[i + 5], s6 = srcA[i + 6], s7 = srcA[i + 7];
      a0 += bf2f(pin[s0 * 40 + lane]);
      a1 += bf2f(pin[s1 * 40 + lane]);
      a2 += bf2f(pin[s2 * 40 + lane]);
      a3 += bf2f(pin[s3 * 40 + lane]);
      a0 += bf2f(pin[s4 * 40 + lane]);
      a1 += bf2f(pin[s5 * 40 + lane]);
      a2 += bf2f(pin[s6 * 40 + lane]);
      a3 += bf2f(pin[s7 * 40 + lane]);
    }
    for (; i + 4 <= e; i += 4){
      int s0 = srcA[i], s1 = srcA[i + 1], s2 = srcA[i + 2], s3 = srcA[i + 3];
      a0 += bf2f(pin[s0 * 40 + lane]);
      a1 += bf2f(pin[s1 * 40 + lane]);
      a2 += bf2f(pin[s2 * 40 + lane]);
      a3 += bf2f(pin[s3 * 40 + lane]);
    }
    for (; i < e; ++i) a0 += bf2f(pin[srcA[i] * 40 + lane]);
    v = dis[node] * ((a0 + a1) + (a2 + a3));
  }
  outp[(size_t)node * 40 + lane] = a * v + (1.f - a) * ft[(size_t)node * 40 + lane];
}

extern "C" void kernel_launch(void* const* d_in, const int* in_sizes, int n_in,
                              void* d_out, int out_size, void* d_ws, size_t ws_size,
                              hipStream_t stream)
{
  const float* x     = (const float*)d_in[0];
  const int*   ei    = (const int*)d_in[1];
  const float* linit = (const float*)d_in[2];
  const int*   mask  = (const int*)d_in[3];
  const float* hard  = (const float*)d_in[4];
  const float* w1    = (const float*)d_in[5];
  const float* b1    = (const float*)d_in[6];
  const float* w2    = (const float*)d_in[7];
  const float* b2    = (const float*)d_in[8];
  const float* alpha = (const float*)d_in[9];
  float* out = (float*)d_out;

  const int N   = in_sizes[3];        // 100000
  const int E   = in_sizes[1] / 2;    // 3200000
  const int K1  = in_sizes[0] / N;    // 512
  const int HID = in_sizes[6];        // 256

  char* ws = (char*)d_ws;
  size_t sXB = (size_t)N * K1 * 2;    // x_bf16 region, reused for graph arrays
  size_t sH  = (size_t)N * HID * 2;   // h_bf16 region, reused for ps buffers

  unsigned short* xb  = (unsigned short*)(ws);
  unsigned short* hb  = (unsigned short*)(ws + sXB);
  unsigned short* w1b = (unsigned short*)(ws + sXB + sH);
  unsigned short* w2p = (unsigned short*)(ws + sXB + sH + (size_t)HID * K1 * 2);
  float*          ft  = (float*)(ws + sXB + sH + (size_t)HID * K1 * 2 + 48 * 256 * 2);

  // ft region (16MB) transient use: Gdeg (8N ints, 3.2MB) + Gcnt (3.2MB) +
  // eRank (u16 x E, 6.4MB) = 12.8MB. All consumed before gemm2 writes ft.
  // Fully overwritten by k_mega -> no memset.
  int* Gdeg = (int*)ft;
  int* Gcnt = Gdeg + (size_t)NCH * N;
  unsigned short* eRank = (unsigned short*)(Gcnt + (size_t)NCH * N);

  // remaining graph arrays alias the xb region (touched only after gemm1 consumed xb)
  char* g = ws;
  int*   srcA = (int*)g;                      g += (size_t)(E + N) * 4;
  float* dis  = (float*)g;                    g += (size_t)N * 4;
  float* dis2 = (float*)g;                    g += (size_t)N * 4;
  int*   offs = (int*)g;                      g += (size_t)(N + 64) * 4;
  int*   bsum = (int*)g;                      g += 1024;
  int*   list = (int*)g;                      g += (size_t)N * 4;
  int*   nUn  = (int*)g;                      g += 256;

  // ps buffers alias hb region (touched only after gemm2 consumed hb)
  unsigned* psI = (unsigned*)(ws + sXB);
  unsigned* psA = (unsigned*)(ws + sXB + (size_t)N * 40 * 2);
  unsigned* psB = (unsigned*)(ws + sXB + (size_t)N * 40 * 4);

  // 1) fused [deg-hist | cnt-hist+rank | f2bf(x) | f2bf(w1) | w2pad]
  int nx  = N * K1;
  int nw1 = HID * K1;
  int CH  = (((E + NCH - 1) / NCH) + 1023) & ~1023;   // 1024-aligned chunk
  int HB2 = 2 * NCH * NRNG;
  int XB  = (nx / 8 + 255) / 256;
  int W1B = (nw1 / 8 + 255) / 256;
  int W2B = 48;
  k_mega<<<HB2 + XB + W1B + W2B, 256, 0, stream>>>(ei, E, CH, Gdeg, Gcnt, eRank, N,
                                                   x, xb, nx, w1, w1b, nw1, w2, w2p,
                                                   XB, W1B);

  // 2) GEMM1 (consumes xb, w1b)
  dim3 g1((N + 127) / 128, HID / 128);
  k_gemm1<<<g1, 256, 0, stream>>>(xb, w1b, b1, hb, N);

  // 3) graph prep (xb region dead after gemm1); nUn zeroed here
  hipMemsetAsync(nUn, 0, 4, stream);
  k_dis<<<(N + 255) / 256, 256, 0, stream>>>(Gdeg, mask, dis, dis2, list, nUn, N);
  int nsb = (N + 1023) / 1024;
  k_scan1<<<nsb, 256, 0, stream>>>(Gcnt, offs, bsum, N);
  k_scan2<<<1, 256, 0, stream>>>(bsum, nsb, offs + N);
  k_scan3<<<nsb, 256, 0, stream>>>(offs, bsum, srcA, N);
  k_prefixG<<<(N + 255) / 256, 256, 0, stream>>>(Gcnt, offs, N);

  // 4) E-parallel atomic-free scatter (consumes Gcnt bases + eRank, ft region)
  k_scatter_flat<<<(E + 1023) / 1024, 256, 0, stream>>>(ei, E, CH >> 10, Gcnt, N, eRank, srcA);

  // 5) GEMM2 (writes ft over dead Gdeg/Gcnt/eRank) + scaled-label init
  k_gemm2<<<(N + 63) / 64, 256, 0, stream>>>(hb, w2p, b2, ft, N);
  k_init_ps<<<(N * 20 + 255) / 256, 256, 0, stream>>>(linit, hard, dis, mask, psI, psA, psB, N * 20);

  // 6) 9 prop steps + fused final
  const unsigned short* pin = (const unsigned short*)psI;
  for (int s = 0; s < 9; ++s){
    unsigned short* po = (unsigned short*)((s & 1) ? psB : psA);
    k_prop<<<(N + 3) / 4, 256, 0, stream>>>(offs, srcA, list, nUn, dis2, pin, po);
    pin = po;
  }
  k_prop_final<<<(N + 3) / 4, 256, 0, stream>>>(offs, srcA, dis, pin, mask, hard, alpha, ft, out, N);
}

// Round 6
// 1018.104 us; speedup vs baseline: 1.1014x; 1.1014x over previous
//
#include <hip/hip_runtime.h>
#include <stdint.h>

typedef __attribute__((ext_vector_type(8))) short bf16x8;
typedef __attribute__((ext_vector_type(4))) float f32x4;

#define NCH 8           // edge chunks (chunk size CH is 1024-aligned, host-computed)
#define NRNG 8          // node-id ranges
#define HWORDS 6272     // packed u32 words (2 u16 bins each) >= ceil(12500/2); 25088B LDS

static __device__ __forceinline__ unsigned short f2bf(float f){
  unsigned int u = __float_as_uint(f);
  return (unsigned short)((u + 0x7fffu + ((u >> 16) & 1u)) >> 16);
}
static __device__ __forceinline__ float bf2f(unsigned short h){
  return __uint_as_float(((unsigned int)h) << 16);
}

static __device__ __forceinline__ void gld_lds16(const void* g, void* l){
  __builtin_amdgcn_global_load_lds((__attribute__((address_space(1))) void*)(void*)g,
                                   (__attribute__((address_space(3))) void*)l, 16, 0, 0);
}

// ---------------- fused: LDS-binned edge histograms (+rank record) + fp32->bf16 ----------------
// Rounds 0-2: gfx950 global atomics are always memory-side (~32B write-through,
// ~25G/s) -> all graph-build atomics must be LDS. Round 3: standalone scatter
// was parallelism-starved. Round 4: hist blocks were LATENCY-starved (1 block/CU,
// 1 load in flight -> ~500cy per iter, 333us). Fix: software-pipeline the scan
// with 8 independent int4 loads in flight per thread (8 separately-coalesced
// 256-vec regions per outer iteration). Round 5: container-level infra failure,
// source audited (bounds/alignment clean) and resubmitted unchanged.
// blocks: [0,HB): deg-hist; [HB,2HB): cnt-hist+rank; then x/w1 converts, w2pad.
__global__ __launch_bounds__(256) void k_mega(
    const int* __restrict__ ei, int E, int CH,
    int* __restrict__ Gdeg, int* __restrict__ Gcnt,
    unsigned short* __restrict__ eRank, int Nn,
    const float* __restrict__ x, unsigned short* __restrict__ xb, int nx,
    const float* __restrict__ w1, unsigned short* __restrict__ w1b, int nw1,
    const float* __restrict__ w2, unsigned short* __restrict__ w2p,
    int XB, int W1B)
{
  __shared__ unsigned hist[HWORDS];
  const int HB = NCH * NRNG;
  int b = blockIdx.x;
  int tid = threadIdx.x;
  if (b < 2 * HB){
    int isCnt = (b >= HB);
    int hb = isCnt ? b - HB : b;
    int c = hb >> 3, r = hb & 7;                 // NRNG = 8
    int BIN = (Nn + NRNG - 1) / NRNG;
    int r0 = r * BIN;
    int bc = Nn - r0; if (bc > BIN) bc = BIN;
    int words = (bc + 1) >> 1;
    const int* keys = ei + (isCnt ? E : 0);
    int* G = (isCnt ? Gcnt : Gdeg) + (size_t)c * Nn + r0;
    for (int i = tid; i < words; i += 256) hist[i] = 0;
    __syncthreads();
    int cs = c * CH;
    int ce = E - cs; if (ce > CH) ce = CH;       // edges in this chunk
    const int* kc = keys + cs;
    const int4* vp = (const int4*)kc;            // cs is 1024-edge aligned -> 16B ok
    int totalVec = ce >> 2;
    int nOuter = totalVec >> 11;                 // 2048 vecs (8/thread) per outer
    if (isCnt){
      unsigned short* rk = eRank + cs;
      for (int it = 0; it < nOuter; ++it){
        int base = it << 11;
        int4 a[8];
#pragma unroll
        for (int k = 0; k < 8; ++k) a[k] = vp[base + (k << 8) + tid];
#pragma unroll
        for (int k = 0; k < 8; ++k){
          int e0 = (base + (k << 8) + tid) << 2;
          int t, sh; unsigned ret;
#define CNTR(KK, UU) \
          t = KK - r0; \
          if ((unsigned)t < (unsigned)bc){ \
            sh = (t & 1) << 4; \
            ret = atomicAdd(&hist[t >> 1], 1u << sh); \
            rk[e0 + UU] = (unsigned short)((ret >> sh) & 0xffffu); \
          }
          CNTR(a[k].x, 0) CNTR(a[k].y, 1) CNTR(a[k].z, 2) CNTR(a[k].w, 3)
        }
      }
      for (int v = (nOuter << 11) + tid; v < totalVec; v += 256){
        int4 a = vp[v];
        int e0 = v << 2;
        int t, sh; unsigned ret;
        CNTR(a.x, 0) CNTR(a.y, 1) CNTR(a.z, 2) CNTR(a.w, 3)
#undef CNTR
      }
      for (int j = (totalVec << 2) + tid; j < ce; j += 256){
        int t = kc[j] - r0;
        if ((unsigned)t < (unsigned)bc){
          int sh = (t & 1) << 4;
          unsigned ret = atomicAdd(&hist[t >> 1], 1u << sh);
          rk[j] = (unsigned short)((ret >> sh) & 0xffffu);
        }
      }
    } else {
      for (int it = 0; it < nOuter; ++it){
        int base = it << 11;
        int4 a[8];
#pragma unroll
        for (int k = 0; k < 8; ++k) a[k] = vp[base + (k << 8) + tid];
#pragma unroll
        for (int k = 0; k < 8; ++k){
          int t;
          t = a[k].x - r0; if ((unsigned)t < (unsigned)bc) atomicAdd(&hist[t >> 1], 1u << ((t & 1) << 4));
          t = a[k].y - r0; if ((unsigned)t < (unsigned)bc) atomicAdd(&hist[t >> 1], 1u << ((t & 1) << 4));
          t = a[k].z - r0; if ((unsigned)t < (unsigned)bc) atomicAdd(&hist[t >> 1], 1u << ((t & 1) << 4));
          t = a[k].w - r0; if ((unsigned)t < (unsigned)bc) atomicAdd(&hist[t >> 1], 1u << ((t & 1) << 4));
        }
      }
      for (int v = (nOuter << 11) + tid; v < totalVec; v += 256){
        int4 a = vp[v];
        int t;
        t = a.x - r0; if ((unsigned)t < (unsigned)bc) atomicAdd(&hist[t >> 1], 1u << ((t & 1) << 4));
        t = a.y - r0; if ((unsigned)t < (unsigned)bc) atomicAdd(&hist[t >> 1], 1u << ((t & 1) << 4));
        t = a.z - r0; if ((unsigned)t < (unsigned)bc) atomicAdd(&hist[t >> 1], 1u << ((t & 1) << 4));
        t = a.w - r0; if ((unsigned)t < (unsigned)bc) atomicAdd(&hist[t >> 1], 1u << ((t & 1) << 4));
      }
      for (int j = (totalVec << 2) + tid; j < ce; j += 256){
        int t = kc[j] - r0;
        if ((unsigned)t < (unsigned)bc) atomicAdd(&hist[t >> 1], 1u << ((t & 1) << 4));
      }
    }
    __syncthreads();
    for (int i = tid; i < bc; i += 256)
      G[i] = (int)((hist[i >> 1] >> ((i & 1) << 4)) & 0xffffu);
  } else if (b < 2 * HB + XB){
    int i = ((b - 2 * HB) * 256 + tid) * 8;
    if (i + 8 <= nx){
      float4 a = *(const float4*)(x + i);
      float4 c = *(const float4*)(x + i + 4);
      ushort4 r0 = { f2bf(a.x), f2bf(a.y), f2bf(a.z), f2bf(a.w) };
      ushort4 r1 = { f2bf(c.x), f2bf(c.y), f2bf(c.z), f2bf(c.w) };
      *(ushort4*)(xb + i) = r0;
      *(ushort4*)(xb + i + 4) = r1;
    } else {
      for (int j = i; j < nx; ++j) xb[j] = f2bf(x[j]);
    }
  } else if (b < 2 * HB + XB + W1B){
    int i = ((b - 2 * HB - XB) * 256 + tid) * 8;
    if (i + 8 <= nw1){
      float4 a = *(const float4*)(w1 + i);
      float4 c = *(const float4*)(w1 + i + 4);
      ushort4 r0 = { f2bf(a.x), f2bf(a.y), f2bf(a.z), f2bf(a.w) };
      ushort4 r1 = { f2bf(c.x), f2bf(c.y), f2bf(c.z), f2bf(c.w) };
      *(ushort4*)(w1b + i) = r0;
      *(ushort4*)(w1b + i + 4) = r1;
    } else {
      for (int j = i; j < nw1; ++j) w1b[j] = f2bf(w1[j]);
    }
  } else {
    int e = (b - 2 * HB - XB - W1B) * 256 + tid;   // 48*256 elems
    int r = e >> 8, c = e & 255;
    float v = (r < 40) ? w2[r * 256 + c] : 0.f;
    w2p[e] = f2bf(v);
  }
}

// ---------------- GEMM1: H = relu(X @ W1^T + b1), bf16 in, bf16 out ----------------
__global__ __launch_bounds__(256) void k_gemm1(
    const unsigned short* __restrict__ A,   // M x 512 bf16
    const unsigned short* __restrict__ B,   // 256 x 512 bf16
    const float* __restrict__ bias,         // 256 fp32
    unsigned short* __restrict__ H,         // M x 256 bf16
    int M)
{
  __shared__ __align__(16) unsigned short lA[128 * 32];
  __shared__ __align__(16) unsigned short lB[128 * 32];
  const int K = 512;
  int tid = threadIdx.x;
  int wave = tid >> 6, lane = tid & 63;
  int quad = lane >> 4, l16 = lane & 15;
  int rowBase = blockIdx.x * 128;
  int colBase = blockIdx.y * 128;
  int wm = (wave & 1) * 64, wn = (wave >> 1) * 64;

  f32x4 acc[4][4] = {};

  for (int k0 = 0; k0 < K; k0 += 32){
#pragma unroll
    for (int i = 0; i < 2; ++i){
      int issue = wave * 2 + i;
      int s = issue * 64 + lane;
      int r = s >> 2;
      int c = (s & 3) ^ (r & 3);
      int gr = rowBase + r; if (gr >= M) gr = M - 1;
      gld_lds16(A + (size_t)gr * K + k0 + c * 8, (char*)lA + issue * 1024);
      gld_lds16(B + (size_t)(colBase + r) * K + k0 + c * 8, (char*)lB + issue * 1024);
    }
    __syncthreads();
    bf16x8 af[4], bf[4];
#pragma unroll
    for (int mt = 0; mt < 4; ++mt){
      int r = wm + mt * 16 + l16;
      af[mt] = *(const bf16x8*)&lA[r * 32 + ((quad ^ (r & 3)) * 8)];
    }
#pragma unroll
    for (int nt = 0; nt < 4; ++nt){
      int r = wn + nt * 16 + l16;
      bf[nt] = *(const bf16x8*)&lB[r * 32 + ((quad ^ (r & 3)) * 8)];
    }
#pragma unroll
    for (int mt = 0; mt < 4; ++mt)
#pragma unroll
      for (int nt = 0; nt < 4; ++nt)
        acc[mt][nt] = __builtin_amdgcn_mfma_f32_16x16x32_bf16(af[mt], bf[nt], acc[mt][nt], 0, 0, 0);
    __syncthreads();
  }

#pragma unroll
  for (int nt = 0; nt < 4; ++nt){
    int col = colBase + wn + nt * 16 + l16;
    float bb = bias[col];
#pragma unroll
    for (int mt = 0; mt < 4; ++mt){
#pragma unroll
      for (int rr = 0; rr < 4; ++rr){
        int row = rowBase + wm + mt * 16 + quad * 4 + rr;
        if (row < M){
          float v = acc[mt][nt][rr] + bb;
          v = v > 0.f ? v : 0.f;
          H[(size_t)row * 256 + col] = f2bf(v);
        }
      }
    }
  }
}

// ---------------- GEMM2: FT = H @ W2^T + b2 (fp32 out) ----------------
__global__ __launch_bounds__(256) void k_gemm2(
    const unsigned short* __restrict__ H,
    const unsigned short* __restrict__ W2p,
    const float* __restrict__ b2,
    float* __restrict__ ft,
    int M)
{
  __shared__ __align__(16) unsigned short lW[48 * 264];
  int tid = threadIdx.x;
  int wave = tid >> 6, lane = tid & 63;
  int quad = lane >> 4, l16 = lane & 15;

  for (int idx = tid; idx < 48 * 32; idx += 256){
    int r = idx >> 5, c = idx & 31;
    *(bf16x8*)&lW[r * 264 + c * 8] = *(const bf16x8*)&W2p[r * 256 + c * 8];
  }
  __syncthreads();

  int row0 = blockIdx.x * 64 + wave * 16;
  f32x4 acc[3] = {};
  int r = row0 + l16; if (r >= M) r = M - 1;
#pragma unroll
  for (int ks = 0; ks < 8; ++ks){
    bf16x8 af = *(const bf16x8*)&H[(size_t)r * 256 + ks * 32 + quad * 8];
#pragma unroll
    for (int nt = 0; nt < 3; ++nt){
      bf16x8 bf = *(const bf16x8*)&lW[(nt * 16 + l16) * 264 + ks * 32 + quad * 8];
      acc[nt] = __builtin_amdgcn_mfma_f32_16x16x32_bf16(af, bf, acc[nt], 0, 0, 0);
    }
  }
#pragma unroll
  for (int nt = 0; nt < 3; ++nt){
    int col = nt * 16 + l16;
    if (col < 40){
      float bb = b2[col];
#pragma unroll
      for (int rr = 0; rr < 4; ++rr){
        int row = row0 + quad * 4 + rr;
        if (row < M) ft[(size_t)row * 40 + col] = acc[nt][rr] + bb;
      }
    }
  }
}

// ---------------- graph prep ----------------
__global__ void k_dis(const int* __restrict__ Gdeg, const int* __restrict__ mask,
                      float* __restrict__ dis, float* __restrict__ dis2,
                      int* __restrict__ list, int* __restrict__ nUn, int n){
  int i = blockIdx.x * 256 + threadIdx.x;
  if (i < n){
    int dsum = 0;
#pragma unroll
    for (int c = 0; c < NCH; ++c) dsum += Gdeg[(size_t)c * n + i];
    float d = rsqrtf((float)(dsum + 1));
    dis[i] = d; dis2[i] = d * d;
    if (!mask[i]){ int pos = atomicAdd(nUn, 1); list[pos] = i; }
  }
}

// exclusive scan over in-counts (sum of Gcnt chunks + 1 self, ALL nodes;
// masked nodes' CSC lists are built but never read)
__global__ void k_scan1(const int* __restrict__ Gcnt,
                        int* __restrict__ out, int* __restrict__ bsum, int n){
  __shared__ int ts[256];
  int tid = threadIdx.x;
  int base = blockIdx.x * 1024 + tid * 4;
  int v0 = 0, v1 = 0, v2 = 0, v3 = 0;
  if (base + 4 <= n){
#pragma unroll
    for (int c = 0; c < NCH; ++c){
      int4 cc = *(const int4*)(Gcnt + (size_t)c * n + base);
      v0 += cc.x; v1 += cc.y; v2 += cc.z; v3 += cc.w;
    }
    v0 += 1; v1 += 1; v2 += 1; v3 += 1;
  } else if (base < n){
    int vv[4] = {0, 0, 0, 0};
    for (int j = 0; j < 4 && base + j < n; ++j){
      int s = 0;
      for (int c = 0; c < NCH; ++c) s += Gcnt[(size_t)c * n + base + j];
      vv[j] = s + 1;
    }
    v0 = vv[0]; v1 = vv[1]; v2 = vv[2]; v3 = vv[3];
  }
  int tot = v0 + v1 + v2 + v3;
  ts[tid] = tot; __syncthreads();
  int val = tot;
  for (int d = 1; d < 256; d <<= 1){
    int t = (tid >= d) ? ts[tid - d] : 0;
    __syncthreads();
    val += t; ts[tid] = val;
    __syncthreads();
  }
  int ex = val - tot;
  if (base     < n) out[base]     = ex;
  if (base + 1 < n) out[base + 1] = ex + v0;
  if (base + 2 < n) out[base + 2] = ex + v0 + v1;
  if (base + 3 < n) out[base + 3] = ex + v0 + v1 + v2;
  if (tid == 255) bsum[blockIdx.x] = val;
}
__global__ void k_scan2(int* __restrict__ bsum, int nb, int* __restrict__ offN){
  __shared__ int ts[256];
  int tid = threadIdx.x;
  int v = (tid < nb) ? bsum[tid] : 0;
  ts[tid] = v; __syncthreads();
  int val = v;
  for (int d = 1; d < 256; d <<= 1){
    int t = (tid >= d) ? ts[tid - d] : 0;
    __syncthreads();
    val += t; ts[tid] = val;
    __syncthreads();
  }
  if (tid < nb) bsum[tid] = val - v;
  if (tid == 255) *offN = val;
}
// finalize offsets; write self-loop entry for ALL nodes
__global__ void k_scan3(int* __restrict__ off, const int* __restrict__ bsum,
                        int* __restrict__ srcA, int n){
  int base = blockIdx.x * 1024 + threadIdx.x * 4;
  int add = bsum[blockIdx.x];
#pragma unroll
  for (int i = 0; i < 4; ++i){
    int j = base + i;
    if (j < n){
      int v = off[j] + add; off[j] = v;
      srcA[v] = j;
    }
  }
}

// turn Gcnt[c][key] counts into per-(chunk,key) scatter bases:
// base[c][key] = offs[key] + 1(self) + sum_{c'<c} Gcnt[c'][key]
__global__ void k_prefixG(int* __restrict__ Gcnt, const int* __restrict__ offs, int n){
  int i = blockIdx.x * 256 + threadIdx.x;
  if (i >= n) return;
  int s = offs[i] + 1;
#pragma unroll
  for (int c = 0; c < NCH; ++c){
    int t = Gcnt[(size_t)c * n + i];
    Gcnt[(size_t)c * n + i] = s;
    s += t;
  }
}

// E-parallel atomic-free scatter: slot = Gbase[chunk][col] + eRank[e].
// cdiv = CH/1024; CH is 1024-aligned so a 1024-edge block stays in one chunk.
__global__ __launch_bounds__(256) void k_scatter_flat(
    const int* __restrict__ ei, int E, int cdiv,
    const int* __restrict__ Gbase, int n,
    const unsigned short* __restrict__ eRank, int* __restrict__ srcA)
{
  int bid = blockIdx.x;
  int c = bid / cdiv;
  const int* gb = Gbase + (size_t)c * n;
  int e0 = bid * 1024 + threadIdx.x * 4;
  if (e0 + 4 <= E){
    int4 c4 = *(const int4*)(ei + E + e0);
    int4 r4 = *(const int4*)(ei + e0);
    ushort4 k4 = *(const ushort4*)(eRank + e0);
    srcA[gb[c4.x] + k4.x] = r4.x;
    srcA[gb[c4.y] + k4.y] = r4.y;
    srcA[gb[c4.z] + k4.z] = r4.z;
    srcA[gb[c4.w] + k4.w] = r4.w;
  } else {
    for (int e = e0; e < E; ++e)
      srcA[gb[ei[E + e]] + eRank[e]] = ei[e];
  }
}

// scaled-label init (packed u32 = 2 bf16 channels per word, 20 words/node)
__global__ void k_init_ps(const float* __restrict__ linit, const float* __restrict__ hard,
                          const float* __restrict__ dis, const int* __restrict__ mask,
                          unsigned* __restrict__ psI, unsigned* __restrict__ psA,
                          unsigned* __restrict__ psB, int nWords){
  int w = blockIdx.x * 256 + threadIdx.x;
  if (w >= nWords) return;
  int node = w / 20, l = w % 20;
  float d = dis[node];
  float2 li = *(const float2*)(linit + (size_t)node * 40 + 2 * l);
  unsigned lo = f2bf(li.x * d), hi = f2bf(li.y * d);
  psI[w] = lo | (hi << 16);
  if (mask[node]){
    float2 hv = *(const float2*)(hard + (size_t)node * 40 + 2 * l);
    unsigned pk = (unsigned)f2bf(hv.x * d) | ((unsigned)f2bf(hv.y * d) << 16);
    psA[w] = pk; psB[w] = pk;
  }
}

// ---------------- label propagation (8-way unroll) ----------------
// ps_out[c] = dis2[c] * sum_{r in CSC(c)} ps_in[r]   (scaled labels, bf16)
__global__ __launch_bounds__(256) void k_prop(
    const int* __restrict__ offs, const int* __restrict__ srcA,
    const int* __restrict__ list, const int* __restrict__ nUn,
    const float* __restrict__ dis2,
    const unsigned short* __restrict__ pin, unsigned short* __restrict__ pout)
{
  int widx = blockIdx.x * 4 + (threadIdx.x >> 6);
  if (widx >= *nUn) return;
  int node = __builtin_amdgcn_readfirstlane(list[widx]);
  int lane = threadIdx.x & 63;
  if (lane >= 40) return;
  int s = offs[node], e = offs[node + 1];
  float a0 = 0.f, a1 = 0.f, a2 = 0.f, a3 = 0.f;
  int i = s;
  for (; i + 8 <= e; i += 8){
    int s0 = srcA[i],     s1 = srcA[i + 1], s2 = srcA[i + 2], s3 = srcA[i + 3];
    int s4 = srcA[i + 4], s5 = srcA[i + 5], s6 = srcA[i + 6], s7 = srcA[i + 7];
    a0 += bf2f(pin[s0 * 40 + lane]);
    a1 += bf2f(pin[s1 * 40 + lane]);
    a2 += bf2f(pin[s2 * 40 + lane]);
    a3 += bf2f(pin[s3 * 40 + lane]);
    a0 += bf2f(pin[s4 * 40 + lane]);
    a1 += bf2f(pin[s5 * 40 + lane]);
    a2 += bf2f(pin[s6 * 40 + lane]);
    a3 += bf2f(pin[s7 * 40 + lane]);
  }
  for (; i + 4 <= e; i += 4){
    int s0 = srcA[i], s1 = srcA[i + 1], s2 = srcA[i + 2], s3 = srcA[i + 3];
    a0 += bf2f(pin[s0 * 40 + lane]);
    a1 += bf2f(pin[s1 * 40 + lane]);
    a2 += bf2f(pin[s2 * 40 + lane]);
    a3 += bf2f(pin[s3 * 40 + lane]);
  }
  for (; i < e; ++i) a0 += bf2f(pin[srcA[i] * 40 + lane]);
  pout[node * 40 + lane] = f2bf(dis2[node] * ((a0 + a1) + (a2 + a3)));
}

// final step fused with sigmoid-gate combine; covers ALL nodes
__global__ __launch_bounds__(256) void k_prop_final(
    const int* __restrict__ offs, const int* __restrict__ srcA,
    const float* __restrict__ dis, const unsigned short* __restrict__ pin,
    const int* __restrict__ mask, const float* __restrict__ hard,
    const float* __restrict__ alpha, const float* __restrict__ ft,
    float* __restrict__ outp, int n)
{
  int node = blockIdx.x * 4 + (threadIdx.x >> 6);
  if (node >= n) return;
  node = __builtin_amdgcn_readfirstlane(node);
  int lane = threadIdx.x & 63;
  if (lane >= 40) return;
  float a = 1.f / (1.f + __expf(-alpha[node]));
  float v;
  if (mask[node]){
    v = hard[(size_t)node * 40 + lane];
  } else {
    int s = offs[node], e = offs[node + 1];
    float a0 = 0.f, a1 = 0.f, a2 = 0.f, a3 = 0.f;
    int i = s;
    for (; i + 8 <= e; i += 8){
      int s0 = srcA[i],     s1 = srcA[i + 1], s2 = srcA[i + 2], s3 = srcA[i + 3];
      int s4 = srcA[i + 4], s5 = srcA[i + 5], s6 = srcA[i + 6], s7 = srcA[i + 7];
      a0 += bf2f(pin[s0 * 40 + lane]);
      a1 += bf2f(pin[s1 * 40 + lane]);
      a2 += bf2f(pin[s2 * 40 + lane]);
      a3 += bf2f(pin[s3 * 40 + lane]);
      a0 += bf2f(pin[s4 * 40 + lane]);
      a1 += bf2f(pin[s5 * 40 + lane]);
      a2 += bf2f(pin[s6 * 40 + lane]);
      a3 += bf2f(pin[s7 * 40 + lane]);
    }
    for (; i + 4 <= e; i += 4){
      int s0 = srcA[i], s1 = srcA[i + 1], s2 = srcA[i + 2], s3 = srcA[i + 3];
      a0 += bf2f(pin[s0 * 40 + lane]);
      a1 += bf2f(pin[s1 * 40 + lane]);
      a2 += bf2f(pin[s2 * 40 + lane]);
      a3 += bf2f(pin[s3 * 40 + lane]);
    }
    for (; i < e; ++i) a0 += bf2f(pin[srcA[i] * 40 + lane]);
    v = dis[node] * ((a0 + a1) + (a2 + a3));
  }
  outp[(size_t)node * 40 + lane] = a * v + (1.f - a) * ft[(size_t)node * 40 + lane];
}

extern "C" void kernel_launch(void* const* d_in, const int* in_sizes, int n_in,
                              void* d_out, int out_size, void* d_ws, size_t ws_size,
                              hipStream_t stream)
{
  const float* x     = (const float*)d_in[0];
  const int*   ei    = (const int*)d_in[1];
  const float* linit = (const float*)d_in[2];
  const int*   mask  = (const int*)d_in[3];
  const float* hard  = (const float*)d_in[4];
  const float* w1    = (const float*)d_in[5];
  const float* b1    = (const float*)d_in[6];
  const float* w2    = (const float*)d_in[7];
  const float* b2    = (const float*)d_in[8];
  const float* alpha = (const float*)d_in[9];
  float* out = (float*)d_out;

  const int N   = in_sizes[3];        // 100000
  const int E   = in_sizes[1] / 2;    // 3200000
  const int K1  = in_sizes[0] / N;    // 512
  const int HID = in_sizes[6];        // 256

  char* ws = (char*)d_ws;
  size_t sXB = (size_t)N * K1 * 2;    // x_bf16 region, reused for graph arrays
  size_t sH  = (size_t)N * HID * 2;   // h_bf16 region, reused for ps buffers

  unsigned short* xb  = (unsigned short*)(ws);
  unsigned short* hb  = (unsigned short*)(ws + sXB);
  unsigned short* w1b = (unsigned short*)(ws + sXB + sH);
  unsigned short* w2p = (unsigned short*)(ws + sXB + sH + (size_t)HID * K1 * 2);
  float*          ft  = (float*)(ws + sXB + sH + (size_t)HID * K1 * 2 + 48 * 256 * 2);

  // ft region (16MB) transient use: Gdeg (8N ints, 3.2MB) + Gcnt (3.2MB) +
  // eRank (u16 x E, 6.4MB) = 12.8MB. All consumed before gemm2 writes ft.
  // Fully overwritten by k_mega -> no memset.
  int* Gdeg = (int*)ft;
  int* Gcnt = Gdeg + (size_t)NCH * N;
  unsigned short* eRank = (unsigned short*)(Gcnt + (size_t)NCH * N);

  // remaining graph arrays alias the xb region (touched only after gemm1 consumed xb)
  char* g = ws;
  int*   srcA = (int*)g;                      g += (size_t)(E + N) * 4;
  float* dis  = (float*)g;                    g += (size_t)N * 4;
  float* dis2 = (float*)g;                    g += (size_t)N * 4;
  int*   offs = (int*)g;                      g += (size_t)(N + 64) * 4;
  int*   bsum = (int*)g;                      g += 1024;
  int*   list = (int*)g;                      g += (size_t)N * 4;
  int*   nUn  = (int*)g;                      g += 256;

  // ps buffers alias hb region (touched only after gemm2 consumed hb)
  unsigned* psI = (unsigned*)(ws + sXB);
  unsigned* psA = (unsigned*)(ws + sXB + (size_t)N * 40 * 2);
  unsigned* psB = (unsigned*)(ws + sXB + (size_t)N * 40 * 4);

  // 1) fused [deg-hist | cnt-hist+rank | f2bf(x) | f2bf(w1) | w2pad]
  int nx  = N * K1;
  int nw1 = HID * K1;
  int CH  = (((E + NCH - 1) / NCH) + 1023) & ~1023;   // 1024-aligned chunk
  int HB2 = 2 * NCH * NRNG;
  int XB  = (nx / 8 + 255) / 256;
  int W1B = (nw1 / 8 + 255) / 256;
  int W2B = 48;
  k_mega<<<HB2 + XB + W1B + W2B, 256, 0, stream>>>(ei, E, CH, Gdeg, Gcnt, eRank, N,
                                                   x, xb, nx, w1, w1b, nw1, w2, w2p,
                                                   XB, W1B);

  // 2) GEMM1 (consumes xb, w1b)
  dim3 g1((N + 127) / 128, HID / 128);
  k_gemm1<<<g1, 256, 0, stream>>>(xb, w1b, b1, hb, N);

  // 3) graph prep (xb region dead after gemm1); nUn zeroed here
  hipMemsetAsync(nUn, 0, 4, stream);
  k_dis<<<(N + 255) / 256, 256, 0, stream>>>(Gdeg, mask, dis, dis2, list, nUn, N);
  int nsb = (N + 1023) / 1024;
  k_scan1<<<nsb, 256, 0, stream>>>(Gcnt, offs, bsum, N);
  k_scan2<<<1, 256, 0, stream>>>(bsum, nsb, offs + N);
  k_scan3<<<nsb, 256, 0, stream>>>(offs, bsum, srcA, N);
  k_prefixG<<<(N + 255) / 256, 256, 0, stream>>>(Gcnt, offs, N);

  // 4) E-parallel atomic-free scatter (consumes Gcnt bases + eRank, ft region)
  k_scatter_flat<<<(E + 1023) / 1024, 256, 0, stream>>>(ei, E, CH >> 10, Gcnt, N, eRank, srcA);

  // 5) GEMM2 (writes ft over dead Gdeg/Gcnt/eRank) + scaled-label init
  k_gemm2<<<(N + 63) / 64, 256, 0, stream>>>(hb, w2p, b2, ft, N);
  k_init_ps<<<(N * 20 + 255) / 256, 256, 0, stream>>>(linit, hard, dis, mask, psI, psA, psB, N * 20);

  // 6) 9 prop steps + fused final
  const unsigned short* pin = (const unsigned short*)psI;
  for (int s = 0; s < 9; ++s){
    unsigned short* po = (unsigned short*)((s & 1) ? psB : psA);
    k_prop<<<(N + 3) / 4, 256, 0, stream>>>(offs, srcA, list, nUn, dis2, pin, po);
    pin = po;
  }
  k_prop_final<<<(N + 3) / 4, 256, 0, stream>>>(offs, srcA, dis, pin, mask, hard, alpha, ft, out, N);
}

// Round 7
// 957.880 us; speedup vs baseline: 1.1706x; 1.0629x over previous
//
#include <hip/hip_runtime.h>
#include <stdint.h>

typedef __attribute__((ext_vector_type(8))) short bf16x8;
typedef __attribute__((ext_vector_type(4))) float f32x4;

#define NCH 16          // edge chunks (chunk size CH is 1024-aligned, host-computed)
#define NRNG 8          // node-id ranges
#define HWORDS 6272     // packed u32 words (2 u16 bins each) >= ceil(12500/2); 25088B LDS

static __device__ __forceinline__ unsigned short f2bf(float f){
  unsigned int u = __float_as_uint(f);
  return (unsigned short)((u + 0x7fffu + ((u >> 16) & 1u)) >> 16);
}
static __device__ __forceinline__ float bf2f(unsigned short h){
  return __uint_as_float(((unsigned int)h) << 16);
}

static __device__ __forceinline__ void gld_lds16(const void* g, void* l){
  __builtin_amdgcn_global_load_lds((__attribute__((address_space(1))) void*)(void*)g,
                                   (__attribute__((address_space(3))) void*)l, 16, 0, 0);
}

// ---------------- fused: LDS-binned edge histograms (+rank record) + fp32->bf16 ----------------
// Rounds 0-2: gfx950 global atomics are always memory-side -> all graph-build
// atomics must be LDS. Round 4: hist blocks latency-starved; r6 pipelining got
// 333->223us but occupancy stayed 26% — only 128 hist blocks on 256 CUs, each
// 1 wave/SIMD, tail ~170us of serial chunk-scan. Fix: NCH 8->16 => 256 hist
// blocks (every CU busy), per-block scan halves. Footprint kept <=16MB by
// u16 G arrays + in-place partial-sum prefix (no separate base array).
// blocks: [0,HB): deg-hist; [HB,2HB): cnt-hist+rank; then x/w1 converts, w2pad.
__global__ __launch_bounds__(256) void k_mega(
    const int* __restrict__ ei, int E, int CH,
    unsigned short* __restrict__ Gdeg, unsigned short* __restrict__ Gcnt,
    unsigned short* __restrict__ eRank, int Nn,
    const float* __restrict__ x, unsigned short* __restrict__ xb, int nx,
    const float* __restrict__ w1, unsigned short* __restrict__ w1b, int nw1,
    const float* __restrict__ w2, unsigned short* __restrict__ w2p,
    int XB, int W1B)
{
  __shared__ unsigned hist[HWORDS];
  const int HB = NCH * NRNG;
  int b = blockIdx.x;
  int tid = threadIdx.x;
  if (b < 2 * HB){
    int isCnt = (b >= HB);
    int hb = isCnt ? b - HB : b;
    int c = hb >> 3, r = hb & 7;                 // NRNG = 8
    int BIN = (Nn + NRNG - 1) / NRNG;
    int r0 = r * BIN;
    int bc = Nn - r0; if (bc > BIN) bc = BIN;
    int words = (bc + 1) >> 1;
    const int* keys = ei + (isCnt ? E : 0);
    unsigned short* G = (isCnt ? Gcnt : Gdeg) + (size_t)c * Nn + r0;
    for (int i = tid; i < words; i += 256) hist[i] = 0;
    __syncthreads();
    int cs = c * CH;
    int ce = E - cs; if (ce > CH) ce = CH;       // edges in this chunk
    const int* kc = keys + cs;
    const int4* vp = (const int4*)kc;            // cs is 1024-edge aligned -> 16B ok
    int totalVec = ce >> 2;
    int nOuter = totalVec >> 11;                 // 2048 vecs (8/thread) per outer
    if (isCnt){
      unsigned short* rk = eRank + cs;
      for (int it = 0; it < nOuter; ++it){
        int base = it << 11;
        int4 a[8];
#pragma unroll
        for (int k = 0; k < 8; ++k) a[k] = vp[base + (k << 8) + tid];
#pragma unroll
        for (int k = 0; k < 8; ++k){
          int e0 = (base + (k << 8) + tid) << 2;
          int t, sh; unsigned ret;
#define CNTR(KK, UU) \
          t = KK - r0; \
          if ((unsigned)t < (unsigned)bc){ \
            sh = (t & 1) << 4; \
            ret = atomicAdd(&hist[t >> 1], 1u << sh); \
            rk[e0 + UU] = (unsigned short)((ret >> sh) & 0xffffu); \
          }
          CNTR(a[k].x, 0) CNTR(a[k].y, 1) CNTR(a[k].z, 2) CNTR(a[k].w, 3)
        }
      }
      for (int v = (nOuter << 11) + tid; v < totalVec; v += 256){
        int4 a = vp[v];
        int e0 = v << 2;
        int t, sh; unsigned ret;
        CNTR(a.x, 0) CNTR(a.y, 1) CNTR(a.z, 2) CNTR(a.w, 3)
#undef CNTR
      }
      for (int j = (totalVec << 2) + tid; j < ce; j += 256){
        int t = kc[j] - r0;
        if ((unsigned)t < (unsigned)bc){
          int sh = (t & 1) << 4;
          unsigned ret = atomicAdd(&hist[t >> 1], 1u << sh);
          rk[j] = (unsigned short)((ret >> sh) & 0xffffu);
        }
      }
    } else {
      for (int it = 0; it < nOuter; ++it){
        int base = it << 11;
        int4 a[8];
#pragma unroll
        for (int k = 0; k < 8; ++k) a[k] = vp[base + (k << 8) + tid];
#pragma unroll
        for (int k = 0; k < 8; ++k){
          int t;
          t = a[k].x - r0; if ((unsigned)t < (unsigned)bc) atomicAdd(&hist[t >> 1], 1u << ((t & 1) << 4));
          t = a[k].y - r0; if ((unsigned)t < (unsigned)bc) atomicAdd(&hist[t >> 1], 1u << ((t & 1) << 4));
          t = a[k].z - r0; if ((unsigned)t < (unsigned)bc) atomicAdd(&hist[t >> 1], 1u << ((t & 1) << 4));
          t = a[k].w - r0; if ((unsigned)t < (unsigned)bc) atomicAdd(&hist[t >> 1], 1u << ((t & 1) << 4));
        }
      }
      for (int v = (nOuter << 11) + tid; v < totalVec; v += 256){
        int4 a = vp[v];
        int t;
        t = a.x - r0; if ((unsigned)t < (unsigned)bc) atomicAdd(&hist[t >> 1], 1u << ((t & 1) << 4));
        t = a.y - r0; if ((unsigned)t < (unsigned)bc) atomicAdd(&hist[t >> 1], 1u << ((t & 1) << 4));
        t = a.z - r0; if ((unsigned)t < (unsigned)bc) atomicAdd(&hist[t >> 1], 1u << ((t & 1) << 4));
        t = a.w - r0; if ((unsigned)t < (unsigned)bc) atomicAdd(&hist[t >> 1], 1u << ((t & 1) << 4));
      }
      for (int j = (totalVec << 2) + tid; j < ce; j += 256){
        int t = kc[j] - r0;
        if ((unsigned)t < (unsigned)bc) atomicAdd(&hist[t >> 1], 1u << ((t & 1) << 4));
      }
    }
    __syncthreads();
    for (int i = tid; i < bc; i += 256)
      G[i] = (unsigned short)((hist[i >> 1] >> ((i & 1) << 4)) & 0xffffu);
  } else if (b < 2 * HB + XB){
    int i = ((b - 2 * HB) * 256 + tid) * 8;
    if (i + 8 <= nx){
      float4 a = *(const float4*)(x + i);
      float4 c = *(const float4*)(x + i + 4);
      ushort4 r0 = { f2bf(a.x), f2bf(a.y), f2bf(a.z), f2bf(a.w) };
      ushort4 r1 = { f2bf(c.x), f2bf(c.y), f2bf(c.z), f2bf(c.w) };
      *(ushort4*)(xb + i) = r0;
      *(ushort4*)(xb + i + 4) = r1;
    } else {
      for (int j = i; j < nx; ++j) xb[j] = f2bf(x[j]);
    }
  } else if (b < 2 * HB + XB + W1B){
    int i = ((b - 2 * HB - XB) * 256 + tid) * 8;
    if (i + 8 <= nw1){
      float4 a = *(const float4*)(w1 + i);
      float4 c = *(const float4*)(w1 + i + 4);
      ushort4 r0 = { f2bf(a.x), f2bf(a.y), f2bf(a.z), f2bf(a.w) };
      ushort4 r1 = { f2bf(c.x), f2bf(c.y), f2bf(c.z), f2bf(c.w) };
      *(ushort4*)(w1b + i) = r0;
      *(ushort4*)(w1b + i + 4) = r1;
    } else {
      for (int j = i; j < nw1; ++j) w1b[j] = f2bf(w1[j]);
    }
  } else {
    int e = (b - 2 * HB - XB - W1B) * 256 + tid;   // 48*256 elems
    int r = e >> 8, c = e & 255;
    float v = (r < 40) ? w2[r * 256 + c] : 0.f;
    w2p[e] = f2bf(v);
  }
}

// ---------------- GEMM1: H = relu(X @ W1^T + b1), bf16 in, bf16 out ----------------
__global__ __launch_bounds__(256) void k_gemm1(
    const unsigned short* __restrict__ A,   // M x 512 bf16
    const unsigned short* __restrict__ B,   // 256 x 512 bf16
    const float* __restrict__ bias,         // 256 fp32
    unsigned short* __restrict__ H,         // M x 256 bf16
    int M)
{
  __shared__ __align__(16) unsigned short lA[128 * 32];
  __shared__ __align__(16) unsigned short lB[128 * 32];
  const int K = 512;
  int tid = threadIdx.x;
  int wave = tid >> 6, lane = tid & 63;
  int quad = lane >> 4, l16 = lane & 15;
  int rowBase = blockIdx.x * 128;
  int colBase = blockIdx.y * 128;
  int wm = (wave & 1) * 64, wn = (wave >> 1) * 64;

  f32x4 acc[4][4] = {};

  for (int k0 = 0; k0 < K; k0 += 32){
#pragma unroll
    for (int i = 0; i < 2; ++i){
      int issue = wave * 2 + i;
      int s = issue * 64 + lane;
      int r = s >> 2;
      int c = (s & 3) ^ (r & 3);
      int gr = rowBase + r; if (gr >= M) gr = M - 1;
      gld_lds16(A + (size_t)gr * K + k0 + c * 8, (char*)lA + issue * 1024);
      gld_lds16(B + (size_t)(colBase + r) * K + k0 + c * 8, (char*)lB + issue * 1024);
    }
    __syncthreads();
    bf16x8 af[4], bf[4];
#pragma unroll
    for (int mt = 0; mt < 4; ++mt){
      int r = wm + mt * 16 + l16;
      af[mt] = *(const bf16x8*)&lA[r * 32 + ((quad ^ (r & 3)) * 8)];
    }
#pragma unroll
    for (int nt = 0; nt < 4; ++nt){
      int r = wn + nt * 16 + l16;
      bf[nt] = *(const bf16x8*)&lB[r * 32 + ((quad ^ (r & 3)) * 8)];
    }
#pragma unroll
    for (int mt = 0; mt < 4; ++mt)
#pragma unroll
      for (int nt = 0; nt < 4; ++nt)
        acc[mt][nt] = __builtin_amdgcn_mfma_f32_16x16x32_bf16(af[mt], bf[nt], acc[mt][nt], 0, 0, 0);
    __syncthreads();
  }

#pragma unroll
  for (int nt = 0; nt < 4; ++nt){
    int col = colBase + wn + nt * 16 + l16;
    float bb = bias[col];
#pragma unroll
    for (int mt = 0; mt < 4; ++mt){
#pragma unroll
      for (int rr = 0; rr < 4; ++rr){
        int row = rowBase + wm + mt * 16 + quad * 4 + rr;
        if (row < M){
          float v = acc[mt][nt][rr] + bb;
          v = v > 0.f ? v : 0.f;
          H[(size_t)row * 256 + col] = f2bf(v);
        }
      }
    }
  }
}

// ---------------- GEMM2: FT = H @ W2^T + b2 (fp32 out) ----------------
__global__ __launch_bounds__(256) void k_gemm2(
    const unsigned short* __restrict__ H,
    const unsigned short* __restrict__ W2p,
    const float* __restrict__ b2,
    float* __restrict__ ft,
    int M)
{
  __shared__ __align__(16) unsigned short lW[48 * 264];
  int tid = threadIdx.x;
  int wave = tid >> 6, lane = tid & 63;
  int quad = lane >> 4, l16 = lane & 15;

  for (int idx = tid; idx < 48 * 32; idx += 256){
    int r = idx >> 5, c = idx & 31;
    *(bf16x8*)&lW[r * 264 + c * 8] = *(const bf16x8*)&W2p[r * 256 + c * 8];
  }
  __syncthreads();

  int row0 = blockIdx.x * 64 + wave * 16;
  f32x4 acc[3] = {};
  int r = row0 + l16; if (r >= M) r = M - 1;
#pragma unroll
  for (int ks = 0; ks < 8; ++ks){
    bf16x8 af = *(const bf16x8*)&H[(size_t)r * 256 + ks * 32 + quad * 8];
#pragma unroll
    for (int nt = 0; nt < 3; ++nt){
      bf16x8 bf = *(const bf16x8*)&lW[(nt * 16 + l16) * 264 + ks * 32 + quad * 8];
      acc[nt] = __builtin_amdgcn_mfma_f32_16x16x32_bf16(af, bf, acc[nt], 0, 0, 0);
    }
  }
#pragma unroll
  for (int nt = 0; nt < 3; ++nt){
    int col = nt * 16 + l16;
    if (col < 40){
      float bb = b2[col];
#pragma unroll
      for (int rr = 0; rr < 4; ++rr){
        int row = row0 + quad * 4 + rr;
        if (row < M) ft[(size_t)row * 40 + col] = acc[nt][rr] + bb;
      }
    }
  }
}

// ---------------- graph prep ----------------
__global__ void k_dis(const unsigned short* __restrict__ Gdeg, const int* __restrict__ mask,
                      float* __restrict__ dis, float* __restrict__ dis2,
                      int* __restrict__ list, int* __restrict__ nUn, int n){
  int i = blockIdx.x * 256 + threadIdx.x;
  if (i < n){
    int dsum = 0;
#pragma unroll
    for (int c = 0; c < NCH; ++c) dsum += Gdeg[(size_t)c * n + i];
    float d = rsqrtf((float)(dsum + 1));
    dis[i] = d; dis2[i] = d * d;
    if (!mask[i]){ int pos = atomicAdd(nUn, 1); list[pos] = i; }
  }
}

// exclusive scan over in-counts (sum of Gcnt chunks + 1 self, ALL nodes;
// masked nodes' CSC lists are built but never read)
__global__ void k_scan1(const unsigned short* __restrict__ Gcnt,
                        int* __restrict__ out, int* __restrict__ bsum, int n){
  __shared__ int ts[256];
  int tid = threadIdx.x;
  int base = blockIdx.x * 1024 + tid * 4;
  int v0 = 0, v1 = 0, v2 = 0, v3 = 0;
  if (base + 4 <= n){
#pragma unroll
    for (int c = 0; c < NCH; ++c){
      ushort4 cc = *(const ushort4*)(Gcnt + (size_t)c * n + base);
      v0 += cc.x; v1 += cc.y; v2 += cc.z; v3 += cc.w;
    }
    v0 += 1; v1 += 1; v2 += 1; v3 += 1;
  } else if (base < n){
    int vv[4] = {0, 0, 0, 0};
    for (int j = 0; j < 4 && base + j < n; ++j){
      int s = 0;
      for (int c = 0; c < NCH; ++c) s += Gcnt[(size_t)c * n + base + j];
      vv[j] = s + 1;
    }
    v0 = vv[0]; v1 = vv[1]; v2 = vv[2]; v3 = vv[3];
  }
  int tot = v0 + v1 + v2 + v3;
  ts[tid] = tot; __syncthreads();
  int val = tot;
  for (int d = 1; d < 256; d <<= 1){
    int t = (tid >= d) ? ts[tid - d] : 0;
    __syncthreads();
    val += t; ts[tid] = val;
    __syncthreads();
  }
  int ex = val - tot;
  if (base     < n) out[base]     = ex;
  if (base + 1 < n) out[base + 1] = ex + v0;
  if (base + 2 < n) out[base + 2] = ex + v0 + v1;
  if (base + 3 < n) out[base + 3] = ex + v0 + v1 + v2;
  if (tid == 255) bsum[blockIdx.x] = val;
}
__global__ void k_scan2(int* __restrict__ bsum, int nb, int* __restrict__ offN){
  __shared__ int ts[256];
  int tid = threadIdx.x;
  int v = (tid < nb) ? bsum[tid] : 0;
  ts[tid] = v; __syncthreads();
  int val = v;
  for (int d = 1; d < 256; d <<= 1){
    int t = (tid >= d) ? ts[tid - d] : 0;
    __syncthreads();
    val += t; ts[tid] = val;
    __syncthreads();
  }
  if (tid < nb) bsum[tid] = val - v;
  if (tid == 255) *offN = val;
}
// finalize offsets; write self-loop entry for ALL nodes
__global__ void k_scan3(int* __restrict__ off, const int* __restrict__ bsum,
                        int* __restrict__ srcA, int n){
  int base = blockIdx.x * 1024 + threadIdx.x * 4;
  int add = bsum[blockIdx.x];
#pragma unroll
  for (int i = 0; i < 4; ++i){
    int j = base + i;
    if (j < n){
      int v = off[j] + add; off[j] = v;
      srcA[v] = j;
    }
  }
}

// in-place exclusive prefix over chunks: Gcnt[c][i] <- sum_{c'<c} Gcnt[c'][i].
// Per-thread read-all-then-write-all on the SAME i -> race-free, no extra array.
// (u16 partials: max in-degree ~80 << 65536.)
__global__ void k_prefixG(unsigned short* __restrict__ Gcnt, int n){
  int i = blockIdx.x * 256 + threadIdx.x;
  if (i >= n) return;
  unsigned short t[NCH];
#pragma unroll
  for (int c = 0; c < NCH; ++c) t[c] = Gcnt[(size_t)c * n + i];
  int s = 0;
#pragma unroll
  for (int c = 0; c < NCH; ++c){
    Gcnt[(size_t)c * n + i] = (unsigned short)s;
    s += t[c];
  }
}

// E-parallel atomic-free scatter: slot = offs[col] + 1 + part[chunk][col] + eRank[e].
// cdiv = CH/1024; CH is 1024-aligned so a 1024-edge block stays in one chunk.
__global__ __launch_bounds__(256) void k_scatter_flat(
    const int* __restrict__ ei, int E, int cdiv,
    const int* __restrict__ offs, const unsigned short* __restrict__ part, int n,
    const unsigned short* __restrict__ eRank, int* __restrict__ srcA)
{
  int bid = blockIdx.x;
  int c = bid / cdiv;
  const unsigned short* pp = part + (size_t)c * n;
  int e0 = bid * 1024 + threadIdx.x * 4;
  if (e0 + 4 <= E){
    int4 c4 = *(const int4*)(ei + E + e0);
    int4 r4 = *(const int4*)(ei + e0);
    ushort4 k4 = *(const ushort4*)(eRank + e0);
    srcA[offs[c4.x] + 1 + pp[c4.x] + k4.x] = r4.x;
    srcA[offs[c4.y] + 1 + pp[c4.y] + k4.y] = r4.y;
    srcA[offs[c4.z] + 1 + pp[c4.z] + k4.z] = r4.z;
    srcA[offs[c4.w] + 1 + pp[c4.w] + k4.w] = r4.w;
  } else {
    for (int e = e0; e < E; ++e){
      int col = ei[E + e];
      srcA[offs[col] + 1 + pp[col] + eRank[e]] = ei[e];
    }
  }
}

// scaled-label init (packed u32 = 2 bf16 channels per word, 20 words/node)
__global__ void k_init_ps(const float* __restrict__ linit, const float* __restrict__ hard,
                          const float* __restrict__ dis, const int* __restrict__ mask,
                          unsigned* __restrict__ psI, unsigned* __restrict__ psA,
                          unsigned* __restrict__ psB, int nWords){
  int w = blockIdx.x * 256 + threadIdx.x;
  if (w >= nWords) return;
  int node = w / 20, l = w % 20;
  float d = dis[node];
  float2 li = *(const float2*)(linit + (size_t)node * 40 + 2 * l);
  unsigned lo = f2bf(li.x * d), hi = f2bf(li.y * d);
  psI[w] = lo | (hi << 16);
  if (mask[node]){
    float2 hv = *(const float2*)(hard + (size_t)node * 40 + 2 * l);
    unsigned pk = (unsigned)f2bf(hv.x * d) | ((unsigned)f2bf(hv.y * d) << 16);
    psA[w] = pk; psB[w] = pk;
  }
}

// ---------------- label propagation (8-way unroll) ----------------
// ps_out[c] = dis2[c] * sum_{r in CSC(c)} ps_in[r]   (scaled labels, bf16)
__global__ __launch_bounds__(256) void k_prop(
    const int* __restrict__ offs, const int* __restrict__ srcA,
    const int* __restrict__ list, const int* __restrict__ nUn,
    const float* __restrict__ dis2,
    const unsigned short* __restrict__ pin, unsigned short* __restrict__ pout)
{
  int widx = blockIdx.x * 4 + (threadIdx.x >> 6);
  if (widx >= *nUn) return;
  int node = __builtin_amdgcn_readfirstlane(list[widx]);
  int lane = threadIdx.x & 63;
  if (lane >= 40) return;
  int s = offs[node], e = offs[node + 1];
  float a0 = 0.f, a1 = 0.f, a2 = 0.f, a3 = 0.f;
  int i = s;
  for (; i + 8 <= e; i += 8){
    int s0 = srcA[i],     s1 = srcA[i + 1], s2 = srcA[i + 2], s3 = srcA[i + 3];
    int s4 = srcA[i + 4], s5 = srcA[i + 5], s6 = srcA[i + 6], s7 = srcA[i + 7];
    a0 += bf2f(pin[s0 * 40 + lane]);
    a1 += bf2f(pin[s1 * 40 + lane]);
    a2 += bf2f(pin[s2 * 40 + lane]);
    a3 += bf2f(pin[s3 * 40 + lane]);
    a0 += bf2f(pin[s4 * 40 + lane]);
    a1 += bf2f(pin[s5 * 40 + lane]);
    a2 += bf2f(pin[s6 * 40 + lane]);
    a3 += bf2f(pin[s7 * 40 + lane]);
  }
  for (; i + 4 <= e; i += 4){
    int s0 = srcA[i], s1 = srcA[i + 1], s2 = srcA[i + 2], s3 = srcA[i + 3];
    a0 += bf2f(pin[s0 * 40 + lane]);
    a1 += bf2f(pin[s1 * 40 + lane]);
    a2 += bf2f(pin[s2 * 40 + lane]);
    a3 += bf2f(pin[s3 * 40 + lane]);
  }
  for (; i < e; ++i) a0 += bf2f(pin[srcA[i] * 40 + lane]);
  pout[node * 40 + lane] = f2bf(dis2[node] * ((a0 + a1) + (a2 + a3)));
}

// final step fused with sigmoid-gate combine; covers ALL nodes
__global__ __launch_bounds__(256) void k_prop_final(
    const int* __restrict__ offs, const int* __restrict__ srcA,
    const float* __restrict__ dis, const unsigned short* __restrict__ pin,
    const int* __restrict__ mask, const float* __restrict__ hard,
    const float* __restrict__ alpha, const float* __restrict__ ft,
    float* __restrict__ outp, int n)
{
  int node = blockIdx.x * 4 + (threadIdx.x >> 6);
  if (node >= n) return;
  node = __builtin_amdgcn_readfirstlane(node);
  int lane = threadIdx.x & 63;
  if (lane >= 40) return;
  float a = 1.f / (1.f + __expf(-alpha[node]));
  float v;
  if (mask[node]){
    v = hard[(size_t)node * 40 + lane];
  } else {
    int s = offs[node], e = offs[node + 1];
    float a0 = 0.f, a1 = 0.f, a2 = 0.f, a3 = 0.f;
    int i = s;
    for (; i + 8 <= e; i += 8){
      int s0 = srcA[i],     s1 = srcA[i + 1], s2 = srcA[i + 2], s3 = srcA[i + 3];
      int s4 = srcA[i + 4], s5 = srcA[i + 5], s6 = srcA[i + 6], s7 = srcA[i + 7];
      a0 += bf2f(pin[s0 * 40 + lane]);
      a1 += bf2f(pin[s1 * 40 + lane]);
      a2 += bf2f(pin[s2 * 40 + lane]);
      a3 += bf2f(pin[s3 * 40 + lane]);
      a0 += bf2f(pin[s4 * 40 + lane]);
      a1 += bf2f(pin[s5 * 40 + lane]);
      a2 += bf2f(pin[s6 * 40 + lane]);
      a3 += bf2f(pin[s7 * 40 + lane]);
    }
    for (; i + 4 <= e; i += 4){
      int s0 = srcA[i], s1 = srcA[i + 1], s2 = srcA[i + 2], s3 = srcA[i + 3];
      a0 += bf2f(pin[s0 * 40 + lane]);
      a1 += bf2f(pin[s1 * 40 + lane]);
      a2 += bf2f(pin[s2 * 40 + lane]);
      a3 += bf2f(pin[s3 * 40 + lane]);
    }
    for (; i < e; ++i) a0 += bf2f(pin[srcA[i] * 40 + lane]);
    v = dis[node] * ((a0 + a1) + (a2 + a3));
  }
  outp[(size_t)node * 40 + lane] = a * v + (1.f - a) * ft[(size_t)node * 40 + lane];
}

extern "C" void kernel_launch(void* const* d_in, const int* in_sizes, int n_in,
                              void* d_out, int out_size, void* d_ws, size_t ws_size,
                              hipStream_t stream)
{
  const float* x     = (const float*)d_in[0];
  const int*   ei    = (const int*)d_in[1];
  const float* linit = (const float*)d_in[2];
  const int*   mask  = (const int*)d_in[3];
  const float* hard  = (const float*)d_in[4];
  const float* w1    = (const float*)d_in[5];
  const float* b1    = (const float*)d_in[6];
  const float* w2    = (const float*)d_in[7];
  const float* b2    = (const float*)d_in[8];
  const float* alpha = (const float*)d_in[9];
  float* out = (float*)d_out;

  const int N   = in_sizes[3];        // 100000
  const int E   = in_sizes[1] / 2;    // 3200000
  const int K1  = in_sizes[0] / N;    // 512
  const int HID = in_sizes[6];        // 256

  char* ws = (char*)d_ws;
  size_t sXB = (size_t)N * K1 * 2;    // x_bf16 region, reused for graph arrays
  size_t sH  = (size_t)N * HID * 2;   // h_bf16 region, reused for ps buffers

  unsigned short* xb  = (unsigned short*)(ws);
  unsigned short* hb  = (unsigned short*)(ws + sXB);
  unsigned short* w1b = (unsigned short*)(ws + sXB + sH);
  unsigned short* w2p = (unsigned short*)(ws + sXB + sH + (size_t)HID * K1 * 2);
  float*          ft  = (float*)(ws + sXB + sH + (size_t)HID * K1 * 2 + 48 * 256 * 2);

  // ft region (16MB) transient use: Gdeg u16[16][N] (3.2MB) + Gcnt u16[16][N]
  // (3.2MB, becomes in-place partial sums) + eRank u16[E] (6.4MB) = 12.8MB.
  // All consumed before gemm2 writes ft. Fully overwritten by k_mega -> no memset.
  unsigned short* Gdeg  = (unsigned short*)ft;
  unsigned short* Gcnt  = Gdeg + (size_t)NCH * N;
  unsigned short* eRank = Gcnt + (size_t)NCH * N;

  // remaining graph arrays alias the xb region (touched only after gemm1 consumed xb)
  char* g = ws;
  int*   srcA = (int*)g;                      g += (size_t)(E + N) * 4;
  float* dis  = (float*)g;                    g += (size_t)N * 4;
  float* dis2 = (float*)g;                    g += (size_t)N * 4;
  int*   offs = (int*)g;                      g += (size_t)(N + 64) * 4;
  int*   bsum = (int*)g;                      g += 1024;
  int*   list = (int*)g;                      g += (size_t)N * 4;
  int*   nUn  = (int*)g;                      g += 256;

  // ps buffers alias hb region (touched only after gemm2 consumed hb)
  unsigned* psI = (unsigned*)(ws + sXB);
  unsigned* psA = (unsigned*)(ws + sXB + (size_t)N * 40 * 2);
  unsigned* psB = (unsigned*)(ws + sXB + (size_t)N * 40 * 4);

  // 1) fused [deg-hist | cnt-hist+rank | f2bf(x) | f2bf(w1) | w2pad]
  int nx  = N * K1;
  int nw1 = HID * K1;
  int CH  = (((E + NCH - 1) / NCH) + 1023) & ~1023;   // 1024-aligned chunk
  int HB2 = 2 * NCH * NRNG;
  int XB  = (nx / 8 + 255) / 256;
  int W1B = (nw1 / 8 + 255) / 256;
  int W2B = 48;
  k_mega<<<HB2 + XB + W1B + W2B, 256, 0, stream>>>(ei, E, CH, Gdeg, Gcnt, eRank, N,
                                                   x, xb, nx, w1, w1b, nw1, w2, w2p,
                                                   XB, W1B);

  // 2) GEMM1 (consumes xb, w1b)
  dim3 g1((N + 127) / 128, HID / 128);
  k_gemm1<<<g1, 256, 0, stream>>>(xb, w1b, b1, hb, N);

  // 3) graph prep (xb region dead after gemm1); nUn zeroed here
  hipMemsetAsync(nUn, 0, 4, stream);
  k_dis<<<(N + 255) / 256, 256, 0, stream>>>(Gdeg, mask, dis, dis2, list, nUn, N);
  int nsb = (N + 1023) / 1024;
  k_scan1<<<nsb, 256, 0, stream>>>(Gcnt, offs, bsum, N);
  k_scan2<<<1, 256, 0, stream>>>(bsum, nsb, offs + N);
  k_scan3<<<nsb, 256, 0, stream>>>(offs, bsum, srcA, N);
  k_prefixG<<<(N + 255) / 256, 256, 0, stream>>>(Gcnt, N);

  // 4) E-parallel atomic-free scatter (consumes offs + part + eRank)
  k_scatter_flat<<<(E + 1023) / 1024, 256, 0, stream>>>(ei, E, CH >> 10, offs, Gcnt, N, eRank, srcA);

  // 5) GEMM2 (writes ft over dead Gdeg/Gcnt/eRank) + scaled-label init
  k_gemm2<<<(N + 63) / 64, 256, 0, stream>>>(hb, w2p, b2, ft, N);
  k_init_ps<<<(N * 20 + 255) / 256, 256, 0, stream>>>(linit, hard, dis, mask, psI, psA, psB, N * 20);

  // 6) 9 prop steps + fused final
  const unsigned short* pin = (const unsigned short*)psI;
  for (int s = 0; s < 9; ++s){
    unsigned short* po = (unsigned short*)((s & 1) ? psB : psA);
    k_prop<<<(N + 3) / 4, 256, 0, stream>>>(offs, srcA, list, nUn, dis2, pin, po);
    pin = po;
  }
  k_prop_final<<<(N + 3) / 4, 256, 0, stream>>>(offs, srcA, dis, pin, mask, hard, alpha, ft, out, N);
}

// Round 8
// 916.800 us; speedup vs baseline: 1.2231x; 1.0448x over previous
//
#include <hip/hip_runtime.h>
#include <stdint.h>

typedef __attribute__((ext_vector_type(8))) short bf16x8;
typedef __attribute__((ext_vector_type(4))) float f32x4;

#define NCH 16          // edge chunks (chunk size CH is 1024-aligned, host-computed)
#define NRNG 8          // node-id ranges
#define HWORDS 6272     // packed u32 words (2 u16 bins each) >= ceil(12500/2); 25088B LDS
#define PSW 32          // u32 words per node in padded label layout (20 used, 128B stride)

static __device__ __forceinline__ unsigned short f2bf(float f){
  unsigned int u = __float_as_uint(f);
  return (unsigned short)((u + 0x7fffu + ((u >> 16) & 1u)) >> 16);
}
static __device__ __forceinline__ float bf2f(unsigned short h){
  return __uint_as_float(((unsigned int)h) << 16);
}

static __device__ __forceinline__ void gld_lds16(const void* g, void* l){
  __builtin_amdgcn_global_load_lds((__attribute__((address_space(1))) void*)(void*)g,
                                   (__attribute__((address_space(3))) void*)l, 16, 0, 0);
}

// ---------------- fused: LDS-binned edge histograms (+rank record) + fp32->bf16 ----------------
// Rounds 0-2: gfx950 global atomics are always memory-side -> all graph-build
// atomics must be LDS. R4-R7: hist latency-starvation fixed by 8-deep load
// pipelining + 256 hist blocks (NCH=16). k_mega now ~156us (~16% of run).
// blocks: [0,HB): deg-hist; [HB,2HB): cnt-hist+rank; then x/w1 converts, w2pad.
__global__ __launch_bounds__(256) void k_mega(
    const int* __restrict__ ei, int E, int CH,
    unsigned short* __restrict__ Gdeg, unsigned short* __restrict__ Gcnt,
    unsigned short* __restrict__ eRank, int Nn,
    const float* __restrict__ x, unsigned short* __restrict__ xb, int nx,
    const float* __restrict__ w1, unsigned short* __restrict__ w1b, int nw1,
    const float* __restrict__ w2, unsigned short* __restrict__ w2p,
    int XB, int W1B)
{
  __shared__ unsigned hist[HWORDS];
  const int HB = NCH * NRNG;
  int b = blockIdx.x;
  int tid = threadIdx.x;
  if (b < 2 * HB){
    int isCnt = (b >= HB);
    int hb = isCnt ? b - HB : b;
    int c = hb >> 3, r = hb & 7;                 // NRNG = 8
    int BIN = (Nn + NRNG - 1) / NRNG;
    int r0 = r * BIN;
    int bc = Nn - r0; if (bc > BIN) bc = BIN;
    int words = (bc + 1) >> 1;
    const int* keys = ei + (isCnt ? E : 0);
    unsigned short* G = (isCnt ? Gcnt : Gdeg) + (size_t)c * Nn + r0;
    for (int i = tid; i < words; i += 256) hist[i] = 0;
    __syncthreads();
    int cs = c * CH;
    int ce = E - cs; if (ce > CH) ce = CH;       // edges in this chunk
    const int* kc = keys + cs;
    const int4* vp = (const int4*)kc;            // cs is 1024-edge aligned -> 16B ok
    int totalVec = ce >> 2;
    int nOuter = totalVec >> 11;                 // 2048 vecs (8/thread) per outer
    if (isCnt){
      unsigned short* rk = eRank + cs;
      for (int it = 0; it < nOuter; ++it){
        int base = it << 11;
        int4 a[8];
#pragma unroll
        for (int k = 0; k < 8; ++k) a[k] = vp[base + (k << 8) + tid];
#pragma unroll
        for (int k = 0; k < 8; ++k){
          int e0 = (base + (k << 8) + tid) << 2;
          int t, sh; unsigned ret;
#define CNTR(KK, UU) \
          t = KK - r0; \
          if ((unsigned)t < (unsigned)bc){ \
            sh = (t & 1) << 4; \
            ret = atomicAdd(&hist[t >> 1], 1u << sh); \
            rk[e0 + UU] = (unsigned short)((ret >> sh) & 0xffffu); \
          }
          CNTR(a[k].x, 0) CNTR(a[k].y, 1) CNTR(a[k].z, 2) CNTR(a[k].w, 3)
        }
      }
      for (int v = (nOuter << 11) + tid; v < totalVec; v += 256){
        int4 a = vp[v];
        int e0 = v << 2;
        int t, sh; unsigned ret;
        CNTR(a.x, 0) CNTR(a.y, 1) CNTR(a.z, 2) CNTR(a.w, 3)
#undef CNTR
      }
      for (int j = (totalVec << 2) + tid; j < ce; j += 256){
        int t = kc[j] - r0;
        if ((unsigned)t < (unsigned)bc){
          int sh = (t & 1) << 4;
          unsigned ret = atomicAdd(&hist[t >> 1], 1u << sh);
          rk[j] = (unsigned short)((ret >> sh) & 0xffffu);
        }
      }
    } else {
      for (int it = 0; it < nOuter; ++it){
        int base = it << 11;
        int4 a[8];
#pragma unroll
        for (int k = 0; k < 8; ++k) a[k] = vp[base + (k << 8) + tid];
#pragma unroll
        for (int k = 0; k < 8; ++k){
          int t;
          t = a[k].x - r0; if ((unsigned)t < (unsigned)bc) atomicAdd(&hist[t >> 1], 1u << ((t & 1) << 4));
          t = a[k].y - r0; if ((unsigned)t < (unsigned)bc) atomicAdd(&hist[t >> 1], 1u << ((t & 1) << 4));
          t = a[k].z - r0; if ((unsigned)t < (unsigned)bc) atomicAdd(&hist[t >> 1], 1u << ((t & 1) << 4));
          t = a[k].w - r0; if ((unsigned)t < (unsigned)bc) atomicAdd(&hist[t >> 1], 1u << ((t & 1) << 4));
        }
      }
      for (int v = (nOuter << 11) + tid; v < totalVec; v += 256){
        int4 a = vp[v];
        int t;
        t = a.x - r0; if ((unsigned)t < (unsigned)bc) atomicAdd(&hist[t >> 1], 1u << ((t & 1) << 4));
        t = a.y - r0; if ((unsigned)t < (unsigned)bc) atomicAdd(&hist[t >> 1], 1u << ((t & 1) << 4));
        t = a.z - r0; if ((unsigned)t < (unsigned)bc) atomicAdd(&hist[t >> 1], 1u << ((t & 1) << 4));
        t = a.w - r0; if ((unsigned)t < (unsigned)bc) atomicAdd(&hist[t >> 1], 1u << ((t & 1) << 4));
      }
      for (int j = (totalVec << 2) + tid; j < ce; j += 256){
        int t = kc[j] - r0;
        if ((unsigned)t < (unsigned)bc) atomicAdd(&hist[t >> 1], 1u << ((t & 1) << 4));
      }
    }
    __syncthreads();
    for (int i = tid; i < bc; i += 256)
      G[i] = (unsigned short)((hist[i >> 1] >> ((i & 1) << 4)) & 0xffffu);
  } else if (b < 2 * HB + XB){
    int i = ((b - 2 * HB) * 256 + tid) * 8;
    if (i + 8 <= nx){
      float4 a = *(const float4*)(x + i);
      float4 c = *(const float4*)(x + i + 4);
      ushort4 r0 = { f2bf(a.x), f2bf(a.y), f2bf(a.z), f2bf(a.w) };
      ushort4 r1 = { f2bf(c.x), f2bf(c.y), f2bf(c.z), f2bf(c.w) };
      *(ushort4*)(xb + i) = r0;
      *(ushort4*)(xb + i + 4) = r1;
    } else {
      for (int j = i; j < nx; ++j) xb[j] = f2bf(x[j]);
    }
  } else if (b < 2 * HB + XB + W1B){
    int i = ((b - 2 * HB - XB) * 256 + tid) * 8;
    if (i + 8 <= nw1){
      float4 a = *(const float4*)(w1 + i);
      float4 c = *(const float4*)(w1 + i + 4);
      ushort4 r0 = { f2bf(a.x), f2bf(a.y), f2bf(a.z), f2bf(a.w) };
      ushort4 r1 = { f2bf(c.x), f2bf(c.y), f2bf(c.z), f2bf(c.w) };
      *(ushort4*)(w1b + i) = r0;
      *(ushort4*)(w1b + i + 4) = r1;
    } else {
      for (int j = i; j < nw1; ++j) w1b[j] = f2bf(w1[j]);
    }
  } else {
    int e = (b - 2 * HB - XB - W1B) * 256 + tid;   // 48*256 elems
    int r = e >> 8, c = e & 255;
    float v = (r < 40) ? w2[r * 256 + c] : 0.f;
    w2p[e] = f2bf(v);
  }
}

// ---------------- GEMM1: H = relu(X @ W1^T + b1), bf16 in, bf16 out ----------------
__global__ __launch_bounds__(256) void k_gemm1(
    const unsigned short* __restrict__ A,   // M x 512 bf16
    const unsigned short* __restrict__ B,   // 256 x 512 bf16
    const float* __restrict__ bias,         // 256 fp32
    unsigned short* __restrict__ H,         // M x 256 bf16
    int M)
{
  __shared__ __align__(16) unsigned short lA[128 * 32];
  __shared__ __align__(16) unsigned short lB[128 * 32];
  const int K = 512;
  int tid = threadIdx.x;
  int wave = tid >> 6, lane = tid & 63;
  int quad = lane >> 4, l16 = lane & 15;
  int rowBase = blockIdx.x * 128;
  int colBase = blockIdx.y * 128;
  int wm = (wave & 1) * 64, wn = (wave >> 1) * 64;

  f32x4 acc[4][4] = {};

  for (int k0 = 0; k0 < K; k0 += 32){
#pragma unroll
    for (int i = 0; i < 2; ++i){
      int issue = wave * 2 + i;
      int s = issue * 64 + lane;
      int r = s >> 2;
      int c = (s & 3) ^ (r & 3);
      int gr = rowBase + r; if (gr >= M) gr = M - 1;
      gld_lds16(A + (size_t)gr * K + k0 + c * 8, (char*)lA + issue * 1024);
      gld_lds16(B + (size_t)(colBase + r) * K + k0 + c * 8, (char*)lB + issue * 1024);
    }
    __syncthreads();
    bf16x8 af[4], bf[4];
#pragma unroll
    for (int mt = 0; mt < 4; ++mt){
      int r = wm + mt * 16 + l16;
      af[mt] = *(const bf16x8*)&lA[r * 32 + ((quad ^ (r & 3)) * 8)];
    }
#pragma unroll
    for (int nt = 0; nt < 4; ++nt){
      int r = wn + nt * 16 + l16;
      bf[nt] = *(const bf16x8*)&lB[r * 32 + ((quad ^ (r & 3)) * 8)];
    }
#pragma unroll
    for (int mt = 0; mt < 4; ++mt)
#pragma unroll
      for (int nt = 0; nt < 4; ++nt)
        acc[mt][nt] = __builtin_amdgcn_mfma_f32_16x16x32_bf16(af[mt], bf[nt], acc[mt][nt], 0, 0, 0);
    __syncthreads();
  }

#pragma unroll
  for (int nt = 0; nt < 4; ++nt){
    int col = colBase + wn + nt * 16 + l16;
    float bb = bias[col];
#pragma unroll
    for (int mt = 0; mt < 4; ++mt){
#pragma unroll
      for (int rr = 0; rr < 4; ++rr){
        int row = rowBase + wm + mt * 16 + quad * 4 + rr;
        if (row < M){
          float v = acc[mt][nt][rr] + bb;
          v = v > 0.f ? v : 0.f;
          H[(size_t)row * 256 + col] = f2bf(v);
        }
      }
    }
  }
}

// ---------------- GEMM2: FT = H @ W2^T + b2 (fp32 out) ----------------
__global__ __launch_bounds__(256) void k_gemm2(
    const unsigned short* __restrict__ H,
    const unsigned short* __restrict__ W2p,
    const float* __restrict__ b2,
    float* __restrict__ ft,
    int M)
{
  __shared__ __align__(16) unsigned short lW[48 * 264];
  int tid = threadIdx.x;
  int wave = tid >> 6, lane = tid & 63;
  int quad = lane >> 4, l16 = lane & 15;

  for (int idx = tid; idx < 48 * 32; idx += 256){
    int r = idx >> 5, c = idx & 31;
    *(bf16x8*)&lW[r * 264 + c * 8] = *(const bf16x8*)&W2p[r * 256 + c * 8];
  }
  __syncthreads();

  int row0 = blockIdx.x * 64 + wave * 16;
  f32x4 acc[3] = {};
  int r = row0 + l16; if (r >= M) r = M - 1;
#pragma unroll
  for (int ks = 0; ks < 8; ++ks){
    bf16x8 af = *(const bf16x8*)&H[(size_t)r * 256 + ks * 32 + quad * 8];
#pragma unroll
    for (int nt = 0; nt < 3; ++nt){
      bf16x8 bf = *(const bf16x8*)&lW[(nt * 16 + l16) * 264 + ks * 32 + quad * 8];
      acc[nt] = __builtin_amdgcn_mfma_f32_16x16x32_bf16(af, bf, acc[nt], 0, 0, 0);
    }
  }
#pragma unroll
  for (int nt = 0; nt < 3; ++nt){
    int col = nt * 16 + l16;
    if (col < 40){
      float bb = b2[col];
#pragma unroll
      for (int rr = 0; rr < 4; ++rr){
        int row = row0 + quad * 4 + rr;
        if (row < M) ft[(size_t)row * 40 + col] = acc[nt][rr] + bb;
      }
    }
  }
}

// ---------------- graph prep ----------------
__global__ void k_dis(const unsigned short* __restrict__ Gdeg, const int* __restrict__ mask,
                      float* __restrict__ dis, float* __restrict__ dis2,
                      int* __restrict__ list, int* __restrict__ nUn, int n){
  int i = blockIdx.x * 256 + threadIdx.x;
  if (i < n){
    int dsum = 0;
#pragma unroll
    for (int c = 0; c < NCH; ++c) dsum += Gdeg[(size_t)c * n + i];
    float d = rsqrtf((float)(dsum + 1));
    dis[i] = d; dis2[i] = d * d;
    if (!mask[i]){ int pos = atomicAdd(nUn, 1); list[pos] = i; }
  }
}

// exclusive scan over in-counts (sum of Gcnt chunks + 1 self, ALL nodes;
// masked nodes' CSC lists are built but never read)
__global__ void k_scan1(const unsigned short* __restrict__ Gcnt,
                        int* __restrict__ out, int* __restrict__ bsum, int n){
  __shared__ int ts[256];
  int tid = threadIdx.x;
  int base = blockIdx.x * 1024 + tid * 4;
  int v0 = 0, v1 = 0, v2 = 0, v3 = 0;
  if (base + 4 <= n){
#pragma unroll
    for (int c = 0; c < NCH; ++c){
      ushort4 cc = *(const ushort4*)(Gcnt + (size_t)c * n + base);
      v0 += cc.x; v1 += cc.y; v2 += cc.z; v3 += cc.w;
    }
    v0 += 1; v1 += 1; v2 += 1; v3 += 1;
  } else if (base < n){
    int vv[4] = {0, 0, 0, 0};
    for (int j = 0; j < 4 && base + j < n; ++j){
      int s = 0;
      for (int c = 0; c < NCH; ++c) s += Gcnt[(size_t)c * n + base + j];
      vv[j] = s + 1;
    }
    v0 = vv[0]; v1 = vv[1]; v2 = vv[2]; v3 = vv[3];
  }
  int tot = v0 + v1 + v2 + v3;
  ts[tid] = tot; __syncthreads();
  int val = tot;
  for (int d = 1; d < 256; d <<= 1){
    int t = (tid >= d) ? ts[tid - d] : 0;
    __syncthreads();
    val += t; ts[tid] = val;
    __syncthreads();
  }
  int ex = val - tot;
  if (base     < n) out[base]     = ex;
  if (base + 1 < n) out[base + 1] = ex + v0;
  if (base + 2 < n) out[base + 2] = ex + v0 + v1;
  if (base + 3 < n) out[base + 3] = ex + v0 + v1 + v2;
  if (tid == 255) bsum[blockIdx.x] = val;
}
__global__ void k_scan2(int* __restrict__ bsum, int nb, int* __restrict__ offN){
  __shared__ int ts[256];
  int tid = threadIdx.x;
  int v = (tid < nb) ? bsum[tid] : 0;
  ts[tid] = v; __syncthreads();
  int val = v;
  for (int d = 1; d < 256; d <<= 1){
    int t = (tid >= d) ? ts[tid - d] : 0;
    __syncthreads();
    val += t; ts[tid] = val;
    __syncthreads();
  }
  if (tid < nb) bsum[tid] = val - v;
  if (tid == 255) *offN = val;
}
// finalize offsets; write self-loop entry for ALL nodes
__global__ void k_scan3(int* __restrict__ off, const int* __restrict__ bsum,
                        int* __restrict__ srcA, int n){
  int base = blockIdx.x * 1024 + threadIdx.x * 4;
  int add = bsum[blockIdx.x];
#pragma unroll
  for (int i = 0; i < 4; ++i){
    int j = base + i;
    if (j < n){
      int v = off[j] + add; off[j] = v;
      srcA[v] = j;
    }
  }
}

// in-place exclusive prefix over chunks: Gcnt[c][i] <- sum_{c'<c} Gcnt[c'][i].
// Per-thread read-all-then-write-all on the SAME i -> race-free, no extra array.
__global__ void k_prefixG(unsigned short* __restrict__ Gcnt, int n){
  int i = blockIdx.x * 256 + threadIdx.x;
  if (i >= n) return;
  unsigned short t[NCH];
#pragma unroll
  for (int c = 0; c < NCH; ++c) t[c] = Gcnt[(size_t)c * n + i];
  int s = 0;
#pragma unroll
  for (int c = 0; c < NCH; ++c){
    Gcnt[(size_t)c * n + i] = (unsigned short)s;
    s += t[c];
  }
}

// E-parallel atomic-free scatter: slot = offs[col] + 1 + part[chunk][col] + eRank[e].
__global__ __launch_bounds__(256) void k_scatter_flat(
    const int* __restrict__ ei, int E, int cdiv,
    const int* __restrict__ offs, const unsigned short* __restrict__ part, int n,
    const unsigned short* __restrict__ eRank, int* __restrict__ srcA)
{
  int bid = blockIdx.x;
  int c = bid / cdiv;
  const unsigned short* pp = part + (size_t)c * n;
  int e0 = bid * 1024 + threadIdx.x * 4;
  if (e0 + 4 <= E){
    int4 c4 = *(const int4*)(ei + E + e0);
    int4 r4 = *(const int4*)(ei + e0);
    ushort4 k4 = *(const ushort4*)(eRank + e0);
    srcA[offs[c4.x] + 1 + pp[c4.x] + k4.x] = r4.x;
    srcA[offs[c4.y] + 1 + pp[c4.y] + k4.y] = r4.y;
    srcA[offs[c4.z] + 1 + pp[c4.z] + k4.z] = r4.z;
    srcA[offs[c4.w] + 1 + pp[c4.w] + k4.w] = r4.w;
  } else {
    for (int e = e0; e < E; ++e){
      int col = ei[E + e];
      srcA[offs[col] + 1 + pp[col] + eRank[e]] = ei[e];
    }
  }
}

// scaled-label init, PADDED layout: PSW(32) u32 words/node (20 used, 128B stride).
// R7 evidence: prop gathers at 80B stride straddle cache lines ~40% of the time;
// 128B stride makes every source gather exactly one line.
__global__ void k_init_ps(const float* __restrict__ linit, const float* __restrict__ hard,
                          const float* __restrict__ dis, const int* __restrict__ mask,
                          unsigned* __restrict__ psI, unsigned* __restrict__ psA,
                          unsigned* __restrict__ psB, int nWords){
  int w = blockIdx.x * 256 + threadIdx.x;
  if (w >= nWords) return;
  int node = w / 20, l = w % 20;
  float d = dis[node];
  float2 li = *(const float2*)(linit + (size_t)node * 40 + 2 * l);
  unsigned lo = f2bf(li.x * d), hi = f2bf(li.y * d);
  int idx = node * PSW + l;
  psI[idx] = lo | (hi << 16);
  if (mask[node]){
    float2 hv = *(const float2*)(hard + (size_t)node * 40 + 2 * l);
    unsigned pk = (unsigned)f2bf(hv.x * d) | ((unsigned)f2bf(hv.y * d) << 16);
    psA[idx] = pk; psB[idx] = pk;
  }
}

// ---------------- label propagation: 3 nodes/wave, u32-packed channels ----------------
// lane = (g = lane/20 -> node subgroup, cl = lane%20 -> channel word).
// One wave-gather instruction now services 3 sources (3 cache lines, 60 lanes)
// vs 1 source/40 lanes before: 3x fewer VMEM instrs, 1-line gathers.
__global__ __launch_bounds__(256) void k_prop(
    const int* __restrict__ offs, const int* __restrict__ srcA,
    const int* __restrict__ list, const int* __restrict__ nUn,
    const float* __restrict__ dis2,
    const unsigned* __restrict__ pin, unsigned* __restrict__ pout)
{
  int lane = threadIdx.x & 63;
  int g = lane / 20;
  int cl = lane - g * 20;
  int widx = (blockIdx.x * 4 + (threadIdx.x >> 6)) * 3 + g;
  if (g >= 3 || widx >= *nUn) return;
  int node = list[widx];
  int s = offs[node], e = offs[node + 1];
  float lo0 = 0.f, hi0 = 0.f, lo1 = 0.f, hi1 = 0.f;
  int i = s;
  for (; i + 8 <= e; i += 8){
    int s0 = srcA[i],     s1 = srcA[i + 1], s2 = srcA[i + 2], s3 = srcA[i + 3];
    int s4 = srcA[i + 4], s5 = srcA[i + 5], s6 = srcA[i + 6], s7 = srcA[i + 7];
    unsigned w0 = pin[s0 * PSW + cl], w1 = pin[s1 * PSW + cl];
    unsigned w2 = pin[s2 * PSW + cl], w3 = pin[s3 * PSW + cl];
    unsigned w4 = pin[s4 * PSW + cl], w5 = pin[s5 * PSW + cl];
    unsigned w6 = pin[s6 * PSW + cl], w7 = pin[s7 * PSW + cl];
    lo0 += bf2f((unsigned short)w0); hi0 += bf2f((unsigned short)(w0 >> 16));
    lo1 += bf2f((unsigned short)w1); hi1 += bf2f((unsigned short)(w1 >> 16));
    lo0 += bf2f((unsigned short)w2); hi0 += bf2f((unsigned short)(w2 >> 16));
    lo1 += bf2f((unsigned short)w3); hi1 += bf2f((unsigned short)(w3 >> 16));
    lo0 += bf2f((unsigned short)w4); hi0 += bf2f((unsigned short)(w4 >> 16));
    lo1 += bf2f((unsigned short)w5); hi1 += bf2f((unsigned short)(w5 >> 16));
    lo0 += bf2f((unsigned short)w6); hi0 += bf2f((unsigned short)(w6 >> 16));
    lo1 += bf2f((unsigned short)w7); hi1 += bf2f((unsigned short)(w7 >> 16));
  }
  for (; i + 4 <= e; i += 4){
    int s0 = srcA[i], s1 = srcA[i + 1], s2 = srcA[i + 2], s3 = srcA[i + 3];
    unsigned w0 = pin[s0 * PSW + cl], w1 = pin[s1 * PSW + cl];
    unsigned w2 = pin[s2 * PSW + cl], w3 = pin[s3 * PSW + cl];
    lo0 += bf2f((unsigned short)w0); hi0 += bf2f((unsigned short)(w0 >> 16));
    lo1 += bf2f((unsigned short)w1); hi1 += bf2f((unsigned short)(w1 >> 16));
    lo0 += bf2f((unsigned short)w2); hi0 += bf2f((unsigned short)(w2 >> 16));
    lo1 += bf2f((unsigned short)w3); hi1 += bf2f((unsigned short)(w3 >> 16));
  }
  for (; i < e; ++i){
    unsigned w = pin[srcA[i] * PSW + cl];
    lo0 += bf2f((unsigned short)w); hi0 += bf2f((unsigned short)(w >> 16));
  }
  float d = dis2[node];
  unsigned outw = (unsigned)f2bf(d * (lo0 + lo1)) | ((unsigned)f2bf(d * (hi0 + hi1)) << 16);
  pout[node * PSW + cl] = outw;
}

// final step fused with sigmoid-gate combine; covers ALL nodes (3 nodes/wave)
__global__ __launch_bounds__(256) void k_prop_final(
    const int* __restrict__ offs, const int* __restrict__ srcA,
    const float* __restrict__ dis, const unsigned* __restrict__ pin,
    const int* __restrict__ mask, const float* __restrict__ hard,
    const float* __restrict__ alpha, const float* __restrict__ ft,
    float* __restrict__ outp, int n)
{
  int lane = threadIdx.x & 63;
  int g = lane / 20;
  int cl = lane - g * 20;
  int node = (blockIdx.x * 4 + (threadIdx.x >> 6)) * 3 + g;
  if (g >= 3 || node >= n) return;
  float a = 1.f / (1.f + __expf(-alpha[node]));
  float vx, vy;
  if (mask[node]){
    float2 hv = *(const float2*)(hard + (size_t)node * 40 + 2 * cl);
    vx = hv.x; vy = hv.y;
  } else {
    int s = offs[node], e = offs[node + 1];
    float lo0 = 0.f, hi0 = 0.f, lo1 = 0.f, hi1 = 0.f;
    int i = s;
    for (; i + 8 <= e; i += 8){
      int s0 = srcA[i],     s1 = srcA[i + 1], s2 = srcA[i + 2], s3 = srcA[i + 3];
      int s4 = srcA[i + 4], s5 = srcA[i + 5], s6 = srcA[i + 6], s7 = srcA[i + 7];
      unsigned w0 = pin[s0 * PSW + cl], w1 = pin[s1 * PSW + cl];
      unsigned w2 = pin[s2 * PSW + cl], w3 = pin[s3 * PSW + cl];
      unsigned w4 = pin[s4 * PSW + cl], w5 = pin[s5 * PSW + cl];
      unsigned w6 = pin[s6 * PSW + cl], w7 = pin[s7 * PSW + cl];
      lo0 += bf2f((unsigned short)w0); hi0 += bf2f((unsigned short)(w0 >> 16));
      lo1 += bf2f((unsigned short)w1); hi1 += bf2f((unsigned short)(w1 >> 16));
      lo0 += bf2f((unsigned short)w2); hi0 += bf2f((unsigned short)(w2 >> 16));
      lo1 += bf2f((unsigned short)w3); hi1 += bf2f((unsigned short)(w3 >> 16));
      lo0 += bf2f((unsigned short)w4); hi0 += bf2f((unsigned short)(w4 >> 16));
      lo1 += bf2f((unsigned short)w5); hi1 += bf2f((unsigned short)(w5 >> 16));
      lo0 += bf2f((unsigned short)w6); hi0 += bf2f((unsigned short)(w6 >> 16));
      lo1 += bf2f((unsigned short)w7); hi1 += bf2f((unsigned short)(w7 >> 16));
    }
    for (; i + 4 <= e; i += 4){
      int s0 = srcA[i], s1 = srcA[i + 1], s2 = srcA[i + 2], s3 = srcA[i + 3];
      unsigned w0 = pin[s0 * PSW + cl], w1 = pin[s1 * PSW + cl];
      unsigned w2 = pin[s2 * PSW + cl], w3 = pin[s3 * PSW + cl];
      lo0 += bf2f((unsigned short)w0); hi0 += bf2f((unsigned short)(w0 >> 16));
      lo1 += bf2f((unsigned short)w1); hi1 += bf2f((unsigned short)(w1 >> 16));
      lo0 += bf2f((unsigned short)w2); hi0 += bf2f((unsigned short)(w2 >> 16));
      lo1 += bf2f((unsigned short)w3); hi1 += bf2f((unsigned short)(w3 >> 16));
    }
    for (; i < e; ++i){
      unsigned w = pin[srcA[i] * PSW + cl];
      lo0 += bf2f((unsigned short)w); hi0 += bf2f((unsigned short)(w >> 16));
    }
    float d = dis[node];
    vx = d * (lo0 + lo1); vy = d * (hi0 + hi1);
  }
  float2 f = *(const float2*)(ft + (size_t)node * 40 + 2 * cl);
  float2 o;
  o.x = a * vx + (1.f - a) * f.x;
  o.y = a * vy + (1.f - a) * f.y;
  *(float2*)(outp + (size_t)node * 40 + 2 * cl) = o;
}

extern "C" void kernel_launch(void* const* d_in, const int* in_sizes, int n_in,
                              void* d_out, int out_size, void* d_ws, size_t ws_size,
                              hipStream_t stream)
{
  const float* x     = (const float*)d_in[0];
  const int*   ei    = (const int*)d_in[1];
  const float* linit = (const float*)d_in[2];
  const int*   mask  = (const int*)d_in[3];
  const float* hard  = (const float*)d_in[4];
  const float* w1    = (const float*)d_in[5];
  const float* b1    = (const float*)d_in[6];
  const float* w2    = (const float*)d_in[7];
  const float* b2    = (const float*)d_in[8];
  const float* alpha = (const float*)d_in[9];
  float* out = (float*)d_out;

  const int N   = in_sizes[3];        // 100000
  const int E   = in_sizes[1] / 2;    // 3200000
  const int K1  = in_sizes[0] / N;    // 512
  const int HID = in_sizes[6];        // 256

  char* ws = (char*)d_ws;
  size_t sXB = (size_t)N * K1 * 2;    // x_bf16 region, reused for graph arrays
  size_t sH  = (size_t)N * HID * 2;   // h_bf16 region, reused for ps buffers

  unsigned short* xb  = (unsigned short*)(ws);
  unsigned short* hb  = (unsigned short*)(ws + sXB);
  unsigned short* w1b = (unsigned short*)(ws + sXB + sH);
  unsigned short* w2p = (unsigned short*)(ws + sXB + sH + (size_t)HID * K1 * 2);
  float*          ft  = (float*)(ws + sXB + sH + (size_t)HID * K1 * 2 + 48 * 256 * 2);

  // ft region (16MB) transient use: Gdeg u16[16][N] (3.2MB) + Gcnt u16[16][N]
  // (3.2MB, becomes in-place partial sums) + eRank u16[E] (6.4MB) = 12.8MB.
  // All consumed before gemm2 writes ft. Fully overwritten by k_mega -> no memset.
  unsigned short* Gdeg  = (unsigned short*)ft;
  unsigned short* Gcnt  = Gdeg + (size_t)NCH * N;
  unsigned short* eRank = Gcnt + (size_t)NCH * N;

  // remaining graph arrays alias the xb region (touched only after gemm1 consumed xb)
  char* g = ws;
  int*   srcA = (int*)g;                      g += (size_t)(E + N) * 4;
  float* dis  = (float*)g;                    g += (size_t)N * 4;
  float* dis2 = (float*)g;                    g += (size_t)N * 4;
  int*   offs = (int*)g;                      g += (size_t)(N + 64) * 4;
  int*   bsum = (int*)g;                      g += 1024;
  int*   list = (int*)g;                      g += (size_t)N * 4;
  int*   nUn  = (int*)g;                      g += 256;

  // ps buffers alias hb region (touched only after gemm2 consumed hb).
  // PADDED: PSW u32 words per node (128B stride) -> 12.8MB each, 38.4MB < 51.2MB.
  unsigned* psI = (unsigned*)(ws + sXB);
  unsigned* psA = (unsigned*)(ws + sXB + (size_t)N * PSW * 4);
  unsigned* psB = (unsigned*)(ws + sXB + (size_t)N * PSW * 8);

  // 1) fused [deg-hist | cnt-hist+rank | f2bf(x) | f2bf(w1) | w2pad]
  int nx  = N * K1;
  int nw1 = HID * K1;
  int CH  = (((E + NCH - 1) / NCH) + 1023) & ~1023;   // 1024-aligned chunk
  int HB2 = 2 * NCH * NRNG;
  int XB  = (nx / 8 + 255) / 256;
  int W1B = (nw1 / 8 + 255) / 256;
  int W2B = 48;
  k_mega<<<HB2 + XB + W1B + W2B, 256, 0, stream>>>(ei, E, CH, Gdeg, Gcnt, eRank, N,
                                                   x, xb, nx, w1, w1b, nw1, w2, w2p,
                                                   XB, W1B);

  // 2) GEMM1 (consumes xb, w1b)
  dim3 g1((N + 127) / 128, HID / 128);
  k_gemm1<<<g1, 256, 0, stream>>>(xb, w1b, b1, hb, N);

  // 3) graph prep (xb region dead after gemm1); nUn zeroed here
  hipMemsetAsync(nUn, 0, 4, stream);
  k_dis<<<(N + 255) / 256, 256, 0, stream>>>(Gdeg, mask, dis, dis2, list, nUn, N);
  int nsb = (N + 1023) / 1024;
  k_scan1<<<nsb, 256, 0, stream>>>(Gcnt, offs, bsum, N);
  k_scan2<<<1, 256, 0, stream>>>(bsum, nsb, offs + N);
  k_scan3<<<nsb, 256, 0, stream>>>(offs, bsum, srcA, N);
  k_prefixG<<<(N + 255) / 256, 256, 0, stream>>>(Gcnt, N);

  // 4) E-parallel atomic-free scatter (consumes offs + part + eRank)
  k_scatter_flat<<<(E + 1023) / 1024, 256, 0, stream>>>(ei, E, CH >> 10, offs, Gcnt, N, eRank, srcA);

  // 5) GEMM2 (writes ft over dead Gdeg/Gcnt/eRank) + scaled-label init
  k_gemm2<<<(N + 63) / 64, 256, 0, stream>>>(hb, w2p, b2, ft, N);
  k_init_ps<<<(N * 20 + 255) / 256, 256, 0, stream>>>(linit, hard, dis, mask, psI, psA, psB, N * 20);

  // 6) 9 prop steps + fused final (12 nodes per 256-thread block)
  int pgrid = (N + 11) / 12;
  const unsigned* pin = psI;
  for (int s = 0; s < 9; ++s){
    unsigned* po = (s & 1) ? psB : psA;
    k_prop<<<pgrid, 256, 0, stream>>>(offs, srcA, list, nUn, dis2, pin, po);
    pin = po;
  }
  k_prop_final<<<pgrid, 256, 0, stream>>>(offs, srcA, dis, pin, mask, hard, alpha, ft, out, N);
}

// Round 9
// 915.108 us; speedup vs baseline: 1.2253x; 1.0018x over previous
//
#include <hip/hip_runtime.h>
#include <stdint.h>

typedef __attribute__((ext_vector_type(8))) short bf16x8;
typedef __attribute__((ext_vector_type(4))) float f32x4;

#define NCH 16          // edge chunks (chunk size CH is 1024-aligned, host-computed)
#define NRNG 8          // node-id ranges
#define HWORDS 6272     // packed u32 words (2 u16 bins each) >= ceil(12500/2); 25088B LDS
#define PSW 32          // u32 words per node in padded label layout (20 used, 128B stride)

static __device__ __forceinline__ unsigned short f2bf(float f){
  unsigned int u = __float_as_uint(f);
  return (unsigned short)((u + 0x7fffu + ((u >> 16) & 1u)) >> 16);
}
static __device__ __forceinline__ float bf2f(unsigned short h){
  return __uint_as_float(((unsigned int)h) << 16);
}

static __device__ __forceinline__ void gld_lds16(const void* g, void* l){
  __builtin_amdgcn_global_load_lds((__attribute__((address_space(1))) void*)(void*)g,
                                   (__attribute__((address_space(3))) void*)l, 16, 0, 0);
}

// ---------------- fused: LDS-binned edge histograms (+rank record) + fp32->bf16 ----------------
// Rounds 0-2: gfx950 global atomics are always memory-side -> all graph-build
// atomics must be LDS. R4-R7: hist latency-starvation fixed by 8-deep load
// pipelining + 256 hist blocks (NCH=16). k_mega ~155us (~17% of run).
// blocks: [0,HB): deg-hist; [HB,2HB): cnt-hist+rank; then x/w1 converts, w2pad.
__global__ __launch_bounds__(256) void k_mega(
    const int* __restrict__ ei, int E, int CH,
    unsigned short* __restrict__ Gdeg, unsigned short* __restrict__ Gcnt,
    unsigned short* __restrict__ eRank, int Nn,
    const float* __restrict__ x, unsigned short* __restrict__ xb, int nx,
    const float* __restrict__ w1, unsigned short* __restrict__ w1b, int nw1,
    const float* __restrict__ w2, unsigned short* __restrict__ w2p,
    int XB, int W1B)
{
  __shared__ unsigned hist[HWORDS];
  const int HB = NCH * NRNG;
  int b = blockIdx.x;
  int tid = threadIdx.x;
  if (b < 2 * HB){
    int isCnt = (b >= HB);
    int hb = isCnt ? b - HB : b;
    int c = hb >> 3, r = hb & 7;                 // NRNG = 8
    int BIN = (Nn + NRNG - 1) / NRNG;
    int r0 = r * BIN;
    int bc = Nn - r0; if (bc > BIN) bc = BIN;
    int words = (bc + 1) >> 1;
    const int* keys = ei + (isCnt ? E : 0);
    unsigned short* G = (isCnt ? Gcnt : Gdeg) + (size_t)c * Nn + r0;
    for (int i = tid; i < words; i += 256) hist[i] = 0;
    __syncthreads();
    int cs = c * CH;
    int ce = E - cs; if (ce > CH) ce = CH;       // edges in this chunk
    const int* kc = keys + cs;
    const int4* vp = (const int4*)kc;            // cs is 1024-edge aligned -> 16B ok
    int totalVec = ce >> 2;
    int nOuter = totalVec >> 11;                 // 2048 vecs (8/thread) per outer
    if (isCnt){
      unsigned short* rk = eRank + cs;
      for (int it = 0; it < nOuter; ++it){
        int base = it << 11;
        int4 a[8];
#pragma unroll
        for (int k = 0; k < 8; ++k) a[k] = vp[base + (k << 8) + tid];
#pragma unroll
        for (int k = 0; k < 8; ++k){
          int e0 = (base + (k << 8) + tid) << 2;
          int t, sh; unsigned ret;
#define CNTR(KK, UU) \
          t = KK - r0; \
          if ((unsigned)t < (unsigned)bc){ \
            sh = (t & 1) << 4; \
            ret = atomicAdd(&hist[t >> 1], 1u << sh); \
            rk[e0 + UU] = (unsigned short)((ret >> sh) & 0xffffu); \
          }
          CNTR(a[k].x, 0) CNTR(a[k].y, 1) CNTR(a[k].z, 2) CNTR(a[k].w, 3)
        }
      }
      for (int v = (nOuter << 11) + tid; v < totalVec; v += 256){
        int4 a = vp[v];
        int e0 = v << 2;
        int t, sh; unsigned ret;
        CNTR(a.x, 0) CNTR(a.y, 1) CNTR(a.z, 2) CNTR(a.w, 3)
#undef CNTR
      }
      for (int j = (totalVec << 2) + tid; j < ce; j += 256){
        int t = kc[j] - r0;
        if ((unsigned)t < (unsigned)bc){
          int sh = (t & 1) << 4;
          unsigned ret = atomicAdd(&hist[t >> 1], 1u << sh);
          rk[j] = (unsigned short)((ret >> sh) & 0xffffu);
        }
      }
    } else {
      for (int it = 0; it < nOuter; ++it){
        int base = it << 11;
        int4 a[8];
#pragma unroll
        for (int k = 0; k < 8; ++k) a[k] = vp[base + (k << 8) + tid];
#pragma unroll
        for (int k = 0; k < 8; ++k){
          int t;
          t = a[k].x - r0; if ((unsigned)t < (unsigned)bc) atomicAdd(&hist[t >> 1], 1u << ((t & 1) << 4));
          t = a[k].y - r0; if ((unsigned)t < (unsigned)bc) atomicAdd(&hist[t >> 1], 1u << ((t & 1) << 4));
          t = a[k].z - r0; if ((unsigned)t < (unsigned)bc) atomicAdd(&hist[t >> 1], 1u << ((t & 1) << 4));
          t = a[k].w - r0; if ((unsigned)t < (unsigned)bc) atomicAdd(&hist[t >> 1], 1u << ((t & 1) << 4));
        }
      }
      for (int v = (nOuter << 11) + tid; v < totalVec; v += 256){
        int4 a = vp[v];
        int t;
        t = a.x - r0; if ((unsigned)t < (unsigned)bc) atomicAdd(&hist[t >> 1], 1u << ((t & 1) << 4));
        t = a.y - r0; if ((unsigned)t < (unsigned)bc) atomicAdd(&hist[t >> 1], 1u << ((t & 1) << 4));
        t = a.z - r0; if ((unsigned)t < (unsigned)bc) atomicAdd(&hist[t >> 1], 1u << ((t & 1) << 4));
        t = a.w - r0; if ((unsigned)t < (unsigned)bc) atomicAdd(&hist[t >> 1], 1u << ((t & 1) << 4));
      }
      for (int j = (totalVec << 2) + tid; j < ce; j += 256){
        int t = kc[j] - r0;
        if ((unsigned)t < (unsigned)bc) atomicAdd(&hist[t >> 1], 1u << ((t & 1) << 4));
      }
    }
    __syncthreads();
    for (int i = tid; i < bc; i += 256)
      G[i] = (unsigned short)((hist[i >> 1] >> ((i & 1) << 4)) & 0xffffu);
  } else if (b < 2 * HB + XB){
    int i = ((b - 2 * HB) * 256 + tid) * 8;
    if (i + 8 <= nx){
      float4 a = *(const float4*)(x + i);
      float4 c = *(const float4*)(x + i + 4);
      ushort4 r0 = { f2bf(a.x), f2bf(a.y), f2bf(a.z), f2bf(a.w) };
      ushort4 r1 = { f2bf(c.x), f2bf(c.y), f2bf(c.z), f2bf(c.w) };
      *(ushort4*)(xb + i) = r0;
      *(ushort4*)(xb + i + 4) = r1;
    } else {
      for (int j = i; j < nx; ++j) xb[j] = f2bf(x[j]);
    }
  } else if (b < 2 * HB + XB + W1B){
    int i = ((b - 2 * HB - XB) * 256 + tid) * 8;
    if (i + 8 <= nw1){
      float4 a = *(const float4*)(w1 + i);
      float4 c = *(const float4*)(w1 + i + 4);
      ushort4 r0 = { f2bf(a.x), f2bf(a.y), f2bf(a.z), f2bf(a.w) };
      ushort4 r1 = { f2bf(c.x), f2bf(c.y), f2bf(c.z), f2bf(c.w) };
      *(ushort4*)(w1b + i) = r0;
      *(ushort4*)(w1b + i + 4) = r1;
    } else {
      for (int j = i; j < nw1; ++j) w1b[j] = f2bf(w1[j]);
    }
  } else {
    int e = (b - 2 * HB - XB - W1B) * 256 + tid;   // 48*256 elems
    int r = e >> 8, c = e & 255;
    float v = (r < 40) ? w2[r * 256 + c] : 0.f;
    w2p[e] = f2bf(v);
  }
}

// ---------------- GEMM1: H = relu(X @ W1^T + b1), bf16 in, bf16 out ----------------
__global__ __launch_bounds__(256) void k_gemm1(
    const unsigned short* __restrict__ A,   // M x 512 bf16
    const unsigned short* __restrict__ B,   // 256 x 512 bf16
    const float* __restrict__ bias,         // 256 fp32
    unsigned short* __restrict__ H,         // M x 256 bf16
    int M)
{
  __shared__ __align__(16) unsigned short lA[128 * 32];
  __shared__ __align__(16) unsigned short lB[128 * 32];
  const int K = 512;
  int tid = threadIdx.x;
  int wave = tid >> 6, lane = tid & 63;
  int quad = lane >> 4, l16 = lane & 15;
  int rowBase = blockIdx.x * 128;
  int colBase = blockIdx.y * 128;
  int wm = (wave & 1) * 64, wn = (wave >> 1) * 64;

  f32x4 acc[4][4] = {};

  for (int k0 = 0; k0 < K; k0 += 32){
#pragma unroll
    for (int i = 0; i < 2; ++i){
      int issue = wave * 2 + i;
      int s = issue * 64 + lane;
      int r = s >> 2;
      int c = (s & 3) ^ (r & 3);
      int gr = rowBase + r; if (gr >= M) gr = M - 1;
      gld_lds16(A + (size_t)gr * K + k0 + c * 8, (char*)lA + issue * 1024);
      gld_lds16(B + (size_t)(colBase + r) * K + k0 + c * 8, (char*)lB + issue * 1024);
    }
    __syncthreads();
    bf16x8 af[4], bf[4];
#pragma unroll
    for (int mt = 0; mt < 4; ++mt){
      int r = wm + mt * 16 + l16;
      af[mt] = *(const bf16x8*)&lA[r * 32 + ((quad ^ (r & 3)) * 8)];
    }
#pragma unroll
    for (int nt = 0; nt < 4; ++nt){
      int r = wn + nt * 16 + l16;
      bf[nt] = *(const bf16x8*)&lB[r * 32 + ((quad ^ (r & 3)) * 8)];
    }
#pragma unroll
    for (int mt = 0; mt < 4; ++mt)
#pragma unroll
      for (int nt = 0; nt < 4; ++nt)
        acc[mt][nt] = __builtin_amdgcn_mfma_f32_16x16x32_bf16(af[mt], bf[nt], acc[mt][nt], 0, 0, 0);
    __syncthreads();
  }

#pragma unroll
  for (int nt = 0; nt < 4; ++nt){
    int col = colBase + wn + nt * 16 + l16;
    float bb = bias[col];
#pragma unroll
    for (int mt = 0; mt < 4; ++mt){
#pragma unroll
      for (int rr = 0; rr < 4; ++rr){
        int row = rowBase + wm + mt * 16 + quad * 4 + rr;
        if (row < M){
          float v = acc[mt][nt][rr] + bb;
          v = v > 0.f ? v : 0.f;
          H[(size_t)row * 256 + col] = f2bf(v);
        }
      }
    }
  }
}

// ---------------- GEMM2: FT = H @ W2^T + b2 (fp32 out) ----------------
__global__ __launch_bounds__(256) void k_gemm2(
    const unsigned short* __restrict__ H,
    const unsigned short* __restrict__ W2p,
    const float* __restrict__ b2,
    float* __restrict__ ft,
    int M)
{
  __shared__ __align__(16) unsigned short lW[48 * 264];
  int tid = threadIdx.x;
  int wave = tid >> 6, lane = tid & 63;
  int quad = lane >> 4, l16 = lane & 15;

  for (int idx = tid; idx < 48 * 32; idx += 256){
    int r = idx >> 5, c = idx & 31;
    *(bf16x8*)&lW[r * 264 + c * 8] = *(const bf16x8*)&W2p[r * 256 + c * 8];
  }
  __syncthreads();

  int row0 = blockIdx.x * 64 + wave * 16;
  f32x4 acc[3] = {};
  int r = row0 + l16; if (r >= M) r = M - 1;
#pragma unroll
  for (int ks = 0; ks < 8; ++ks){
    bf16x8 af = *(const bf16x8*)&H[(size_t)r * 256 + ks * 32 + quad * 8];
#pragma unroll
    for (int nt = 0; nt < 3; ++nt){
      bf16x8 bf = *(const bf16x8*)&lW[(nt * 16 + l16) * 264 + ks * 32 + quad * 8];
      acc[nt] = __builtin_amdgcn_mfma_f32_16x16x32_bf16(af, bf, acc[nt], 0, 0, 0);
    }
  }
#pragma unroll
  for (int nt = 0; nt < 3; ++nt){
    int col = nt * 16 + l16;
    if (col < 40){
      float bb = b2[col];
#pragma unroll
      for (int rr = 0; rr < 4; ++rr){
        int row = row0 + quad * 4 + rr;
        if (row < M) ft[(size_t)row * 40 + col] = acc[nt][rr] + bb;
      }
    }
  }
}

// ---------------- graph prep ----------------
__global__ void k_dis(const unsigned short* __restrict__ Gdeg, const int* __restrict__ mask,
                      float* __restrict__ dis, float* __restrict__ dis2,
                      int* __restrict__ list, int* __restrict__ nUn, int n){
  int i = blockIdx.x * 256 + threadIdx.x;
  if (i < n){
    int dsum = 0;
#pragma unroll
    for (int c = 0; c < NCH; ++c) dsum += Gdeg[(size_t)c * n + i];
    float d = rsqrtf((float)(dsum + 1));
    dis[i] = d; dis2[i] = d * d;
    if (!mask[i]){ int pos = atomicAdd(nUn, 1); list[pos] = i; }
  }
}

// exclusive scan over in-counts (sum of Gcnt chunks + 1 self, ALL nodes;
// masked nodes' CSC lists are built but never read)
__global__ void k_scan1(const unsigned short* __restrict__ Gcnt,
                        int* __restrict__ out, int* __restrict__ bsum, int n){
  __shared__ int ts[256];
  int tid = threadIdx.x;
  int base = blockIdx.x * 1024 + tid * 4;
  int v0 = 0, v1 = 0, v2 = 0, v3 = 0;
  if (base + 4 <= n){
#pragma unroll
    for (int c = 0; c < NCH; ++c){
      ushort4 cc = *(const ushort4*)(Gcnt + (size_t)c * n + base);
      v0 += cc.x; v1 += cc.y; v2 += cc.z; v3 += cc.w;
    }
    v0 += 1; v1 += 1; v2 += 1; v3 += 1;
  } else if (base < n){
    int vv[4] = {0, 0, 0, 0};
    for (int j = 0; j < 4 && base + j < n; ++j){
      int s = 0;
      for (int c = 0; c < NCH; ++c) s += Gcnt[(size_t)c * n + base + j];
      vv[j] = s + 1;
    }
    v0 = vv[0]; v1 = vv[1]; v2 = vv[2]; v3 = vv[3];
  }
  int tot = v0 + v1 + v2 + v3;
  ts[tid] = tot; __syncthreads();
  int val = tot;
  for (int d = 1; d < 256; d <<= 1){
    int t = (tid >= d) ? ts[tid - d] : 0;
    __syncthreads();
    val += t; ts[tid] = val;
    __syncthreads();
  }
  int ex = val - tot;
  if (base     < n) out[base]     = ex;
  if (base + 1 < n) out[base + 1] = ex + v0;
  if (base + 2 < n) out[base + 2] = ex + v0 + v1;
  if (base + 3 < n) out[base + 3] = ex + v0 + v1 + v2;
  if (tid == 255) bsum[blockIdx.x] = val;
}
__global__ void k_scan2(int* __restrict__ bsum, int nb, int* __restrict__ offN){
  __shared__ int ts[256];
  int tid = threadIdx.x;
  int v = (tid < nb) ? bsum[tid] : 0;
  ts[tid] = v; __syncthreads();
  int val = v;
  for (int d = 1; d < 256; d <<= 1){
    int t = (tid >= d) ? ts[tid - d] : 0;
    __syncthreads();
    val += t; ts[tid] = val;
    __syncthreads();
  }
  if (tid < nb) bsum[tid] = val - v;
  if (tid == 255) *offN = val;
}
// finalize offsets; write self-loop entry for ALL nodes
__global__ void k_scan3(int* __restrict__ off, const int* __restrict__ bsum,
                        int* __restrict__ srcA, int n){
  int base = blockIdx.x * 1024 + threadIdx.x * 4;
  int add = bsum[blockIdx.x];
#pragma unroll
  for (int i = 0; i < 4; ++i){
    int j = base + i;
    if (j < n){
      int v = off[j] + add; off[j] = v;
      srcA[v] = j;
    }
  }
}

// in-place exclusive prefix over chunks: Gcnt[c][i] <- sum_{c'<c} Gcnt[c'][i].
__global__ void k_prefixG(unsigned short* __restrict__ Gcnt, int n){
  int i = blockIdx.x * 256 + threadIdx.x;
  if (i >= n) return;
  unsigned short t[NCH];
#pragma unroll
  for (int c = 0; c < NCH; ++c) t[c] = Gcnt[(size_t)c * n + i];
  int s = 0;
#pragma unroll
  for (int c = 0; c < NCH; ++c){
    Gcnt[(size_t)c * n + i] = (unsigned short)s;
    s += t[c];
  }
}

// E-parallel atomic-free scatter: slot = offs[col] + 1 + part[chunk][col] + eRank[e].
__global__ __launch_bounds__(256) void k_scatter_flat(
    const int* __restrict__ ei, int E, int cdiv,
    const int* __restrict__ offs, const unsigned short* __restrict__ part, int n,
    const unsigned short* __restrict__ eRank, int* __restrict__ srcA)
{
  int bid = blockIdx.x;
  int c = bid / cdiv;
  const unsigned short* pp = part + (size_t)c * n;
  int e0 = bid * 1024 + threadIdx.x * 4;
  if (e0 + 4 <= E){
    int4 c4 = *(const int4*)(ei + E + e0);
    int4 r4 = *(const int4*)(ei + e0);
    ushort4 k4 = *(const ushort4*)(eRank + e0);
    srcA[offs[c4.x] + 1 + pp[c4.x] + k4.x] = r4.x;
    srcA[offs[c4.y] + 1 + pp[c4.y] + k4.y] = r4.y;
    srcA[offs[c4.z] + 1 + pp[c4.z] + k4.z] = r4.z;
    srcA[offs[c4.w] + 1 + pp[c4.w] + k4.w] = r4.w;
  } else {
    for (int e = e0; e < E; ++e){
      int col = ei[E + e];
      srcA[offs[col] + 1 + pp[col] + eRank[e]] = ei[e];
    }
  }
}

// scaled-label init, PADDED layout: PSW(32) u32 words/node (20 used, 128B stride).
__global__ void k_init_ps(const float* __restrict__ linit, const float* __restrict__ hard,
                          const float* __restrict__ dis, const int* __restrict__ mask,
                          unsigned* __restrict__ psI, unsigned* __restrict__ psA,
                          unsigned* __restrict__ psB, int nWords){
  int w = blockIdx.x * 256 + threadIdx.x;
  if (w >= nWords) return;
  int node = w / 20, l = w % 20;
  float d = dis[node];
  float2 li = *(const float2*)(linit + (size_t)node * 40 + 2 * l);
  unsigned lo = f2bf(li.x * d), hi = f2bf(li.y * d);
  int idx = node * PSW + l;
  psI[idx] = lo | (hi << 16);
  if (mask[node]){
    float2 hv = *(const float2*)(hard + (size_t)node * 40 + 2 * l);
    unsigned pk = (unsigned)f2bf(hv.x * d) | ((unsigned)f2bf(hv.y * d) << 16);
    psA[idx] = pk; psB[idx] = pk;
  }
}

// ---------------- label propagation: 12 nodes/wave, uint4 (16B) per lane ----------------
// R8 post-mortem: prop is gather-INSTRUCTION-rate bound, not BW bound (132MB
// useful/step = ~8us of L2 BW; measured ~50us). Maximize bytes/instr: lane =
// (g=lane/5 node, q=lane%5 quarter); each lane gathers uint4 = 16B, 5 lanes
// cover the 80B node record. One gather instr = 12 lines / 960B useful
// (4x round 8). Gather instrs/step: 550K -> 137K.
#define ACC8(W) \
    c0 += bf2f((unsigned short)(W.x)); c1 += bf2f((unsigned short)((W.x) >> 16)); \
    c2 += bf2f((unsigned short)(W.y)); c3 += bf2f((unsigned short)((W.y) >> 16)); \
    c4 += bf2f((unsigned short)(W.z)); c5 += bf2f((unsigned short)((W.z) >> 16)); \
    c6 += bf2f((unsigned short)(W.w)); c7 += bf2f((unsigned short)((W.w) >> 16));

__global__ __launch_bounds__(256) void k_prop(
    const int* __restrict__ offs, const int* __restrict__ srcA,
    const int* __restrict__ list, const int* __restrict__ nUn,
    const float* __restrict__ dis2,
    const unsigned* __restrict__ pin, unsigned* __restrict__ pout)
{
  int lane = threadIdx.x & 63;
  int g = lane / 5;
  int q = lane - g * 5;          // 0..4 -> words q*4..q*4+3 (channels 8q..8q+7)
  if (g >= 12) return;
  int widx = (blockIdx.x * 4 + (threadIdx.x >> 6)) * 12 + g;
  if (widx >= *nUn) return;
  int node = list[widx];
  int s = offs[node], e = offs[node + 1];
  const unsigned* base = pin + q * 4;
  float c0 = 0.f, c1 = 0.f, c2 = 0.f, c3 = 0.f, c4 = 0.f, c5 = 0.f, c6 = 0.f, c7 = 0.f;
  int i = s;
  for (; i + 8 <= e; i += 8){
    int s0 = srcA[i],     s1 = srcA[i + 1], s2 = srcA[i + 2], s3 = srcA[i + 3];
    int s4 = srcA[i + 4], s5 = srcA[i + 5], s6 = srcA[i + 6], s7 = srcA[i + 7];
    uint4 w0 = *(const uint4*)(base + (size_t)s0 * PSW);
    uint4 w1 = *(const uint4*)(base + (size_t)s1 * PSW);
    uint4 w2 = *(const uint4*)(base + (size_t)s2 * PSW);
    uint4 w3 = *(const uint4*)(base + (size_t)s3 * PSW);
    uint4 w4 = *(const uint4*)(base + (size_t)s4 * PSW);
    uint4 w5 = *(const uint4*)(base + (size_t)s5 * PSW);
    uint4 w6 = *(const uint4*)(base + (size_t)s6 * PSW);
    uint4 w7 = *(const uint4*)(base + (size_t)s7 * PSW);
    ACC8(w0) ACC8(w1) ACC8(w2) ACC8(w3) ACC8(w4) ACC8(w5) ACC8(w6) ACC8(w7)
  }
  for (; i + 4 <= e; i += 4){
    int s0 = srcA[i], s1 = srcA[i + 1], s2 = srcA[i + 2], s3 = srcA[i + 3];
    uint4 w0 = *(const uint4*)(base + (size_t)s0 * PSW);
    uint4 w1 = *(const uint4*)(base + (size_t)s1 * PSW);
    uint4 w2 = *(const uint4*)(base + (size_t)s2 * PSW);
    uint4 w3 = *(const uint4*)(base + (size_t)s3 * PSW);
    ACC8(w0) ACC8(w1) ACC8(w2) ACC8(w3)
  }
  for (; i < e; ++i){
    uint4 w = *(const uint4*)(base + (size_t)srcA[i] * PSW);
    ACC8(w)
  }
  float d = dis2[node];
  uint4 o;
  o.x = (unsigned)f2bf(d * c0) | ((unsigned)f2bf(d * c1) << 16);
  o.y = (unsigned)f2bf(d * c2) | ((unsigned)f2bf(d * c3) << 16);
  o.z = (unsigned)f2bf(d * c4) | ((unsigned)f2bf(d * c5) << 16);
  o.w = (unsigned)f2bf(d * c6) | ((unsigned)f2bf(d * c7) << 16);
  *(uint4*)(pout + (size_t)node * PSW + q * 4) = o;
}

// final step fused with sigmoid-gate combine; covers ALL nodes (12 nodes/wave)
__global__ __launch_bounds__(256) void k_prop_final(
    const int* __restrict__ offs, const int* __restrict__ srcA,
    const float* __restrict__ dis, const unsigned* __restrict__ pin,
    const int* __restrict__ mask, const float* __restrict__ hard,
    const float* __restrict__ alpha, const float* __restrict__ ft,
    float* __restrict__ outp, int n)
{
  int lane = threadIdx.x & 63;
  int g = lane / 5;
  int q = lane - g * 5;
  if (g >= 12) return;
  int node = (blockIdx.x * 4 + (threadIdx.x >> 6)) * 12 + g;
  if (node >= n) return;
  float a = 1.f / (1.f + __expf(-alpha[node]));
  float v0, v1, v2, v3, v4, v5, v6, v7;
  if (mask[node]){
    float4 h0 = *(const float4*)(hard + (size_t)node * 40 + q * 8);
    float4 h1 = *(const float4*)(hard + (size_t)node * 40 + q * 8 + 4);
    v0 = h0.x; v1 = h0.y; v2 = h0.z; v3 = h0.w;
    v4 = h1.x; v5 = h1.y; v6 = h1.z; v7 = h1.w;
  } else {
    int s = offs[node], e = offs[node + 1];
    const unsigned* base = pin + q * 4;
    float c0 = 0.f, c1 = 0.f, c2 = 0.f, c3 = 0.f, c4 = 0.f, c5 = 0.f, c6 = 0.f, c7 = 0.f;
    int i = s;
    for (; i + 8 <= e; i += 8){
      int s0 = srcA[i],     s1 = srcA[i + 1], s2 = srcA[i + 2], s3 = srcA[i + 3];
      int s4 = srcA[i + 4], s5 = srcA[i + 5], s6 = srcA[i + 6], s7 = srcA[i + 7];
      uint4 w0 = *(const uint4*)(base + (size_t)s0 * PSW);
      uint4 w1 = *(const uint4*)(base + (size_t)s1 * PSW);
      uint4 w2 = *(const uint4*)(base + (size_t)s2 * PSW);
      uint4 w3 = *(const uint4*)(base + (size_t)s3 * PSW);
      uint4 w4 = *(const uint4*)(base + (size_t)s4 * PSW);
      uint4 w5 = *(const uint4*)(base + (size_t)s5 * PSW);
      uint4 w6 = *(const uint4*)(base + (size_t)s6 * PSW);
      uint4 w7 = *(const uint4*)(base + (size_t)s7 * PSW);
      ACC8(w0) ACC8(w1) ACC8(w2) ACC8(w3) ACC8(w4) ACC8(w5) ACC8(w6) ACC8(w7)
    }
    for (; i + 4 <= e; i += 4){
      int s0 = srcA[i], s1 = srcA[i + 1], s2 = srcA[i + 2], s3 = srcA[i + 3];
      uint4 w0 = *(const uint4*)(base + (size_t)s0 * PSW);
      uint4 w1 = *(const uint4*)(base + (size_t)s1 * PSW);
      uint4 w2 = *(const uint4*)(base + (size_t)s2 * PSW);
      uint4 w3 = *(const uint4*)(base + (size_t)s3 * PSW);
      ACC8(w0) ACC8(w1) ACC8(w2) ACC8(w3)
    }
    for (; i < e; ++i){
      uint4 w = *(const uint4*)(base + (size_t)srcA[i] * PSW);
      ACC8(w)
    }
    float d = dis[node];
    v0 = d * c0; v1 = d * c1; v2 = d * c2; v3 = d * c3;
    v4 = d * c4; v5 = d * c5; v6 = d * c6; v7 = d * c7;
  }
  float4 f0 = *(const float4*)(ft + (size_t)node * 40 + q * 8);
  float4 f1 = *(const float4*)(ft + (size_t)node * 40 + q * 8 + 4);
  float b = 1.f - a;
  float4 o0, o1;
  o0.x = a * v0 + b * f0.x; o0.y = a * v1 + b * f0.y;
  o0.z = a * v2 + b * f0.z; o0.w = a * v3 + b * f0.w;
  o1.x = a * v4 + b * f1.x; o1.y = a * v5 + b * f1.y;
  o1.z = a * v6 + b * f1.z; o1.w = a * v7 + b * f1.w;
  *(float4*)(outp + (size_t)node * 40 + q * 8) = o0;
  *(float4*)(outp + (size_t)node * 40 + q * 8 + 4) = o1;
}

extern "C" void kernel_launch(void* const* d_in, const int* in_sizes, int n_in,
                              void* d_out, int out_size, void* d_ws, size_t ws_size,
                              hipStream_t stream)
{
  const float* x     = (const float*)d_in[0];
  const int*   ei    = (const int*)d_in[1];
  const float* linit = (const float*)d_in[2];
  const int*   mask  = (const int*)d_in[3];
  const float* hard  = (const float*)d_in[4];
  const float* w1    = (const float*)d_in[5];
  const float* b1    = (const float*)d_in[6];
  const float* w2    = (const float*)d_in[7];
  const float* b2    = (const float*)d_in[8];
  const float* alpha = (const float*)d_in[9];
  float* out = (float*)d_out;

  const int N   = in_sizes[3];        // 100000
  const int E   = in_sizes[1] / 2;    // 3200000
  const int K1  = in_sizes[0] / N;    // 512
  const int HID = in_sizes[6];        // 256

  char* ws = (char*)d_ws;
  size_t sXB = (size_t)N * K1 * 2;    // x_bf16 region, reused for graph arrays
  size_t sH  = (size_t)N * HID * 2;   // h_bf16 region, reused for ps buffers

  unsigned short* xb  = (unsigned short*)(ws);
  unsigned short* hb  = (unsigned short*)(ws + sXB);
  unsigned short* w1b = (unsigned short*)(ws + sXB + sH);
  unsigned short* w2p = (unsigned short*)(ws + sXB + sH + (size_t)HID * K1 * 2);
  float*          ft  = (float*)(ws + sXB + sH + (size_t)HID * K1 * 2 + 48 * 256 * 2);

  // ft region (16MB) transient use: Gdeg u16[16][N] (3.2MB) + Gcnt u16[16][N]
  // (3.2MB, becomes in-place partial sums) + eRank u16[E] (6.4MB) = 12.8MB.
  unsigned short* Gdeg  = (unsigned short*)ft;
  unsigned short* Gcnt  = Gdeg + (size_t)NCH * N;
  unsigned short* eRank = Gcnt + (size_t)NCH * N;

  // remaining graph arrays alias the xb region (touched only after gemm1 consumed xb)
  char* g = ws;
  int*   srcA = (int*)g;                      g += (size_t)(E + N) * 4;
  float* dis  = (float*)g;                    g += (size_t)N * 4;
  float* dis2 = (float*)g;                    g += (size_t)N * 4;
  int*   offs = (int*)g;                      g += (size_t)(N + 64) * 4;
  int*   bsum = (int*)g;                      g += 1024;
  int*   list = (int*)g;                      g += (size_t)N * 4;
  int*   nUn  = (int*)g;                      g += 256;

  // ps buffers alias hb region (touched only after gemm2 consumed hb).
  // PADDED: PSW u32 words per node (128B stride) -> 12.8MB each, 38.4MB < 51.2MB.
  unsigned* psI = (unsigned*)(ws + sXB);
  unsigned* psA = (unsigned*)(ws + sXB + (size_t)N * PSW * 4);
  unsigned* psB = (unsigned*)(ws + sXB + (size_t)N * PSW * 8);

  // 1) fused [deg-hist | cnt-hist+rank | f2bf(x) | f2bf(w1) | w2pad]
  int nx  = N * K1;
  int nw1 = HID * K1;
  int CH  = (((E + NCH - 1) / NCH) + 1023) & ~1023;   // 1024-aligned chunk
  int HB2 = 2 * NCH * NRNG;
  int XB  = (nx / 8 + 255) / 256;
  int W1B = (nw1 / 8 + 255) / 256;
  int W2B = 48;
  k_mega<<<HB2 + XB + W1B + W2B, 256, 0, stream>>>(ei, E, CH, Gdeg, Gcnt, eRank, N,
                                                   x, xb, nx, w1, w1b, nw1, w2, w2p,
                                                   XB, W1B);

  // 2) GEMM1 (consumes xb, w1b)
  dim3 g1((N + 127) / 128, HID / 128);
  k_gemm1<<<g1, 256, 0, stream>>>(xb, w1b, b1, hb, N);

  // 3) graph prep (xb region dead after gemm1); nUn zeroed here
  hipMemsetAsync(nUn, 0, 4, stream);
  k_dis<<<(N + 255) / 256, 256, 0, stream>>>(Gdeg, mask, dis, dis2, list, nUn, N);
  int nsb = (N + 1023) / 1024;
  k_scan1<<<nsb, 256, 0, stream>>>(Gcnt, offs, bsum, N);
  k_scan2<<<1, 256, 0, stream>>>(bsum, nsb, offs + N);
  k_scan3<<<nsb, 256, 0, stream>>>(offs, bsum, srcA, N);
  k_prefixG<<<(N + 255) / 256, 256, 0, stream>>>(Gcnt, N);

  // 4) E-parallel atomic-free scatter (consumes offs + part + eRank)
  k_scatter_flat<<<(E + 1023) / 1024, 256, 0, stream>>>(ei, E, CH >> 10, offs, Gcnt, N, eRank, srcA);

  // 5) GEMM2 (writes ft over dead Gdeg/Gcnt/eRank) + scaled-label init
  k_gemm2<<<(N + 63) / 64, 256, 0, stream>>>(hb, w2p, b2, ft, N);
  k_init_ps<<<(N * 20 + 255) / 256, 256, 0, stream>>>(linit, hard, dis, mask, psI, psA, psB, N * 20);

  // 6) 9 prop steps + fused final (48 nodes per 256-thread block)
  int pgrid = (N + 47) / 48;
  const unsigned* pin = psI;
  for (int s = 0; s < 9; ++s){
    unsigned* po = (s & 1) ? psB : psA;
    k_prop<<<pgrid, 256, 0, stream>>>(offs, srcA, list, nUn, dis2, pin, po);
    pin = po;
  }
  k_prop_final<<<pgrid, 256, 0, stream>>>(offs, srcA, dis, pin, mask, hard, alpha, ft, out, N);
}